// Round 1
// baseline (6747.952 us; speedup 1.0000x reference)
//
#include <hip/hip_runtime.h>
#include <math.h>

#define LL 8192
#define CC 96
#define DINc 96
#define NN 16
#define RR 6
#define KK 8
#define Dd 16
#define Hh 16
#define Ww 32

__constant__ int Pc_[4][3] = {{0,1,2},{1,2,0},{2,0,1},{2,1,0}};

__device__ __forceinline__ float silu_(float x){ return x / (1.f + expf(-x)); }

// ---------------- K1: LN over C at each l ----------------
__global__ void k_ln1(const float* __restrict__ inp, const float* __restrict__ w,
                      const float* __restrict__ b, float* __restrict__ xn) {
    int l = blockIdx.x * blockDim.x + threadIdx.x;
    if (l >= LL) return;
    const float* p = inp + l * CC;
    float m = 0.f;
    for (int c = 0; c < CC; ++c) m += p[c];
    m *= (1.f / CC);
    float v = 0.f;
    for (int c = 0; c < CC; ++c) { float d = p[c] - m; v += d * d; }
    v *= (1.f / CC);
    float r = rsqrtf(v + 1e-6f);
    float* o = xn + l * CC;
    for (int c = 0; c < CC; ++c) o[c] = (p[c] - m) * r * w[c] + b[c];
}

// ---------------- K2: in_proj: xz = xn @ W^T ; x -> channel-major, z -> row-major ----------------
__global__ void k_inproj(const float* __restrict__ xn, const float* __restrict__ W,
                         float* __restrict__ xcm, float* __restrict__ z) {
    int idx = blockIdx.x * blockDim.x + threadIdx.x;
    if (idx >= LL * 2 * DINc) return;
    int e = idx % (2 * DINc);
    int l = idx / (2 * DINc);
    const float* xr = xn + l * CC;
    const float* wr = W + e * CC;
    float s = 0.f;
    for (int c = 0; c < CC; ++c) s += xr[c] * wr[c];
    if (e < DINc) xcm[e * LL + l] = s;
    else          z[l * DINc + (e - DINc)] = s;
}

// ---------------- K3: depthwise conv3d 3x3x3 SAME + SiLU -> xs[0] ----------------
__global__ void k_dwconv(const float* __restrict__ xcm, const float* __restrict__ cw,
                         const float* __restrict__ cb, float* __restrict__ xs0) {
    int idx = blockIdx.x * blockDim.x + threadIdx.x;
    if (idx >= DINc * LL) return;
    int l = idx & (LL - 1);
    int c = idx >> 13;
    int w = l & (Ww - 1);
    int h = (l >> 5) & (Hh - 1);
    int d = l >> 9;
    float s = cb[c];
    const float* xp = xcm + c * LL;
    const float* wp = cw + c * 27;
    for (int kd = -1; kd <= 1; ++kd) {
        int dd = d + kd; if (dd < 0 || dd >= Dd) continue;
        for (int kh = -1; kh <= 1; ++kh) {
            int hh = h + kh; if (hh < 0 || hh >= Hh) continue;
            for (int kw = -1; kw <= 1; ++kw) {
                int ww2 = w + kw; if (ww2 < 0 || ww2 >= Ww) continue;
                s += xp[(dd * Hh + hh) * Ww + ww2] * wp[(kd + 1) * 9 + (kh + 1) * 3 + (kw + 1)];
            }
        }
    }
    xs0[c * LL + l] = silu_(s);
}

// ---------------- K4: build xs[1..7] from xs[0] ----------------
__global__ void k_perm(float* __restrict__ xs) {
    int idx = blockIdx.x * blockDim.x + threadIdx.x;
    if (idx >= 7 * DINc * LL) return;
    int l = idx & (LL - 1);
    int c = (idx >> 13) % DINc;
    int k = idx / (DINc * LL) + 1;  // 1..7
    int i  = (k < 4) ? k : (k - 4);
    int lp = (k < 4) ? l : (LL - 1 - l);
    int p0 = Pc_[i][0], p1 = Pc_[i][1], p2 = Pc_[i][2];
    const int sp[3] = {Dd, Hh, Ww};
    int pd1 = sp[p1], pd2 = sp[p2];
    int i2 = lp % pd2;
    int t  = lp / pd2;
    int i1 = t % pd1;
    int i0 = t / pd1;
    int coord[3];
    coord[p0] = i0; coord[p1] = i1; coord[p2] = i2;
    int o = (coord[0] * Hh + coord[1]) * Ww + coord[2];
    xs[(k * DINc + c) * LL + l] = xs[c * LL + o];
}

// ---------------- K5: x_dbl = einsum('bkdl,ked->bkel'), split dts/B/C ----------------
__global__ void k_xdbl(const float* __restrict__ xs, const float* __restrict__ xpw,
                       float* __restrict__ dtraw, float* __restrict__ Bb, float* __restrict__ Cb) {
    long idx = (long)blockIdx.x * blockDim.x + threadIdx.x;
    if (idx >= (long)KK * 38 * LL) return;
    int l  = idx % LL;
    int ke = idx / LL;
    int e  = ke % 38;
    int k  = ke / 38;
    const float* wp = xpw + (k * 38 + e) * DINc;
    const float* xb = xs + (long)k * DINc * LL + l;
    float s = 0.f;
    for (int d = 0; d < DINc; ++d) s += xb[d * LL] * wp[d];
    if (e < RR)            dtraw[(k * RR + e) * LL + l] = s;
    else if (e < RR + NN)  Bb[(k * NN + (e - RR)) * LL + l] = s;
    else                   Cb[(k * NN + (e - RR - NN)) * LL + l] = s;
}

// ---------------- K7: selective scan (16 lanes per (k,d)), ys written in-place over xs ----------------
__global__ void k_scan(float* __restrict__ xs_ys, const float* __restrict__ dtraw,
                       const float* __restrict__ Bb, const float* __restrict__ Cb,
                       const float* __restrict__ A_logs, const float* __restrict__ dt_w,
                       const float* __restrict__ dt_b, const float* __restrict__ Ds) {
    int t = blockIdx.x * blockDim.x + threadIdx.x;
    int grp = t >> 4;           // (k,d) 0..767
    int n = t & 15;
    if (grp >= KK * DINc) return;
    int k = grp / DINc;
    float A_n = -expf(A_logs[grp * NN + n]);
    float w0 = dt_w[grp * RR + 0], w1 = dt_w[grp * RR + 1], w2 = dt_w[grp * RR + 2];
    float w3 = dt_w[grp * RR + 3], w4 = dt_w[grp * RR + 4], w5 = dt_w[grp * RR + 5];
    float dtb = dt_b[grp];
    float Dv  = Ds[grp];
    const float* drb  = dtraw + (long)k * RR * LL;
    const float* Brow = Bb + (long)(k * NN + n) * LL;
    const float* Crow = Cb + (long)(k * NN + n) * LL;
    float* urow = xs_ys + (long)grp * LL;
    float hc = 0.f;
    for (int l = 0; l < LL; ++l) {
        float dtl = dtb + drb[l] * w0 + drb[LL + l] * w1 + drb[2 * LL + l] * w2
                        + drb[3 * LL + l] * w3 + drb[4 * LL + l] * w4 + drb[5 * LL + l] * w5;
        float dt = (dtl > 20.f) ? dtl : log1pf(expf(dtl));
        float u  = urow[l];
        hc = expf(dt * A_n) * hc + (dt * u) * Brow[l];
        float yv = hc * Crow[l];
        yv += __shfl_xor(yv, 1, 16);
        yv += __shfl_xor(yv, 2, 16);
        yv += __shfl_xor(yv, 4, 16);
        yv += __shfl_xor(yv, 8, 16);
        if (n == 0) urow[l] = yv + Dv * u;
    }
}

// ---------------- K8: inverse-permute + sum 8 directions -> acc (row-major L x DIN) ----------------
__global__ void k_combine(const float* __restrict__ ys, float* __restrict__ acc) {
    int idx = blockIdx.x * blockDim.x + threadIdx.x;
    if (idx >= LL * DINc) return;
    int c = idx % DINc;
    int l = idx / DINc;
    int w = l & (Ww - 1);
    int h = (l >> 5) & (Hh - 1);
    int d = l >> 9;
    int coord[3] = {d, h, w};
    const int sp[3] = {Dd, Hh, Ww};
    float s = 0.f;
    #pragma unroll
    for (int i = 0; i < 4; ++i) {
        int p0 = Pc_[i][0], p1 = Pc_[i][1], p2 = Pc_[i][2];
        int lp = (coord[p0] * sp[p1] + coord[p1]) * sp[p2] + coord[p2];
        s += ys[(long)(i * DINc + c) * LL + lp];
        s += ys[(long)((4 + i) * DINc + c) * LL + (LL - 1 - lp)];
    }
    acc[l * DINc + c] = s;
}

// ---------------- K9: out_norm LN over DIN, * silu(z) ----------------
__global__ void k_outnorm(const float* __restrict__ acc, const float* __restrict__ z,
                          const float* __restrict__ w, const float* __restrict__ b,
                          float* __restrict__ y) {
    int l = blockIdx.x * blockDim.x + threadIdx.x;
    if (l >= LL) return;
    const float* a = acc + l * DINc;
    float m = 0.f;
    for (int c = 0; c < DINc; ++c) m += a[c];
    m *= (1.f / DINc);
    float v = 0.f;
    for (int c = 0; c < DINc; ++c) { float d = a[c] - m; v += d * d; }
    v *= (1.f / DINc);
    float r = rsqrtf(v + 1e-5f);
    for (int c = 0; c < DINc; ++c) {
        float zz = z[l * DINc + c];
        y[l * DINc + c] = ((a[c] - m) * r * w[c] + b[c]) * silu_(zz);
    }
}

// ---------------- K10: attn = y @ out_proj^T ; xafter = inp*skip1 + attn ----------------
__global__ void k_outproj(const float* __restrict__ y, const float* __restrict__ opw,
                          const float* __restrict__ inp, const float* __restrict__ skip1,
                          float* __restrict__ xafter) {
    int idx = blockIdx.x * blockDim.x + threadIdx.x;
    if (idx >= LL * CC) return;
    int c = idx % CC;
    int l = idx / CC;
    const float* yr = y + l * DINc;
    const float* wr = opw + c * DINc;
    float s = 0.f;
    for (int e = 0; e < DINc; ++e) s += yr[e] * wr[e];
    xafter[l * CC + c] = inp[l * CC + c] * skip1[c] + s;
}

// ---------------- K11: LN2 -> channel-major y2 ----------------
__global__ void k_ln2(const float* __restrict__ xafter, const float* __restrict__ w,
                      const float* __restrict__ b, float* __restrict__ y2) {
    int l = blockIdx.x * blockDim.x + threadIdx.x;
    if (l >= LL) return;
    const float* p = xafter + l * CC;
    float m = 0.f;
    for (int c = 0; c < CC; ++c) m += p[c];
    m *= (1.f / CC);
    float v = 0.f;
    for (int c = 0; c < CC; ++c) { float d = p[c] - m; v += d * d; }
    v *= (1.f / CC);
    float r = rsqrtf(v + 1e-5f);
    for (int c = 0; c < CC; ++c) y2[c * LL + l] = (p[c] - m) * r * w[c] + b[c];
}

// ---------------- K12: conv3d 96->32 + exact GELU ----------------
__global__ void k_conv1(const float* __restrict__ y2, const float* __restrict__ w1,
                        const float* __restrict__ b1, float* __restrict__ t1) {
    int idx = blockIdx.x * blockDim.x + threadIdx.x;
    if (idx >= 32 * LL) return;
    int l = idx & (LL - 1);
    int oc = idx >> 13;
    int w = l & (Ww - 1);
    int h = (l >> 5) & (Hh - 1);
    int d = l >> 9;
    float s = b1[oc];
    for (int kd = -1; kd <= 1; ++kd) {
        int dd = d + kd; if (dd < 0 || dd >= Dd) continue;
        for (int kh = -1; kh <= 1; ++kh) {
            int hh = h + kh; if (hh < 0 || hh >= Hh) continue;
            for (int kw = -1; kw <= 1; ++kw) {
                int ww2 = w + kw; if (ww2 < 0 || ww2 >= Ww) continue;
                int nl  = (dd * Hh + hh) * Ww + ww2;
                int tap = (kd + 1) * 9 + (kh + 1) * 3 + (kw + 1);
                const float* wp = w1 + oc * 96 * 27 + tap;
                const float* xp = y2 + nl;
                float a = 0.f;
                for (int ic = 0; ic < 96; ++ic) a += xp[ic * LL] * wp[ic * 27];
                s += a;
            }
        }
    }
    t1[oc * LL + l] = 0.5f * s * (1.f + erff(s * 0.70710678118654752f));
}

// ---------------- K13: conv3d 32->96 ----------------
__global__ void k_conv2(const float* __restrict__ t1, const float* __restrict__ w2,
                        const float* __restrict__ b2, float* __restrict__ t2) {
    int idx = blockIdx.x * blockDim.x + threadIdx.x;
    if (idx >= 96 * LL) return;
    int l = idx & (LL - 1);
    int oc = idx >> 13;
    int w = l & (Ww - 1);
    int h = (l >> 5) & (Hh - 1);
    int d = l >> 9;
    float s = b2[oc];
    for (int kd = -1; kd <= 1; ++kd) {
        int dd = d + kd; if (dd < 0 || dd >= Dd) continue;
        for (int kh = -1; kh <= 1; ++kh) {
            int hh = h + kh; if (hh < 0 || hh >= Hh) continue;
            for (int kw = -1; kw <= 1; ++kw) {
                int ww2 = w + kw; if (ww2 < 0 || ww2 >= Ww) continue;
                int nl  = (dd * Hh + hh) * Ww + ww2;
                int tap = (kd + 1) * 9 + (kh + 1) * 3 + (kw + 1);
                const float* wp = w2 + oc * 32 * 27 + tap;
                const float* xp = t1 + nl;
                float a = 0.f;
                for (int ic = 0; ic < 32; ++ic) a += xp[ic * LL] * wp[ic * 27];
                s += a;
            }
        }
    }
    t2[oc * LL + l] = s;
}

// ---------------- K14a: per-channel spatial mean of t2 ----------------
__global__ void k_mean(const float* __restrict__ t2, float* __restrict__ mbuf) {
    __shared__ float sm[256];
    int c = blockIdx.x;
    float a = 0.f;
    for (int l = threadIdx.x; l < LL; l += 256) a += t2[c * LL + l];
    sm[threadIdx.x] = a;
    __syncthreads();
    for (int o = 128; o > 0; o >>= 1) {
        if (threadIdx.x < o) sm[threadIdx.x] += sm[threadIdx.x + o];
        __syncthreads();
    }
    if (threadIdx.x == 0) mbuf[c] = sm[0] * (1.f / LL);
}

// ---------------- K14b: channel-attention MLP ----------------
__global__ void k_mlp(const float* __restrict__ mbuf, const float* __restrict__ w1,
                      const float* __restrict__ b1, const float* __restrict__ w2,
                      const float* __restrict__ b2, float* __restrict__ v2) {
    __shared__ float v[48];
    int t = threadIdx.x;
    if (t < 48) {
        float s = b1[t];
        for (int c = 0; c < 96; ++c) s += mbuf[c] * w1[t * 96 + c];
        v[t] = fmaxf(s, 0.f);
    }
    __syncthreads();
    if (t < 96) {
        float s = b2[t];
        for (int j = 0; j < 48; ++j) s += v[j] * w2[t * 48 + j];
        v2[t] = 1.f / (1.f + expf(-s));
    }
}

// ---------------- K15: final residual ----------------
__global__ void k_final(const float* __restrict__ xafter, const float* __restrict__ skip2,
                        const float* __restrict__ t2, const float* __restrict__ v2,
                        float* __restrict__ out) {
    int idx = blockIdx.x * blockDim.x + threadIdx.x;
    if (idx >= LL * CC) return;
    int c = idx % CC;
    int l = idx / CC;
    out[l * CC + c] = xafter[l * CC + c] * skip2[c] + t2[c * LL + l] * v2[c];
}

// ---------------- workspace layout (float offsets) ----------------
static const size_t OFF_XS     = 0;                    // 8*96*8192  (xs, then ys in-place)
static const size_t OFF_Z      = 6291456;              // 786432
static const size_t OFF_XCM    = 7077888;              // 786432 (pre-conv x; reused as acc)
static const size_t OFF_XN     = 7864320;              // 786432 (xn; reused as y)
static const size_t OFF_DTRAW  = 8650752;              // 393216
static const size_t OFF_BB     = 9043968;              // 1048576
static const size_t OFF_CB     = 10092544;             // 1048576
static const size_t OFF_XAFTER = 11141120;             // 786432
static const size_t OFF_Y2     = 11927552;             // 786432
static const size_t OFF_T1     = 12713984;             // 262144
static const size_t OFF_T2     = 12976128;             // 786432
static const size_t OFF_MV     = 13762560;             // small

extern "C" void kernel_launch(void* const* d_in, const int* in_sizes, int n_in,
                              void* d_out, int out_size, void* d_ws, size_t ws_size,
                              hipStream_t stream) {
    const float* inp    = (const float*)d_in[0];
    const float* ln1_w  = (const float*)d_in[2];
    const float* ln1_b  = (const float*)d_in[3];
    const float* skip1  = (const float*)d_in[4];
    const float* skip2  = (const float*)d_in[5];
    const float* ln2_w  = (const float*)d_in[6];
    const float* ln2_b  = (const float*)d_in[7];
    const float* inpj   = (const float*)d_in[8];
    const float* conv_w = (const float*)d_in[9];
    const float* conv_b = (const float*)d_in[10];
    const float* xpw    = (const float*)d_in[11];
    const float* dt_w   = (const float*)d_in[12];
    const float* dt_b   = (const float*)d_in[13];
    const float* A_logs = (const float*)d_in[14];
    const float* Ds     = (const float*)d_in[15];
    const float* onw    = (const float*)d_in[16];
    const float* onb    = (const float*)d_in[17];
    const float* opw    = (const float*)d_in[18];
    const float* cab_w1 = (const float*)d_in[19];
    const float* cab_b1 = (const float*)d_in[20];
    const float* cab_w2 = (const float*)d_in[21];
    const float* cab_b2 = (const float*)d_in[22];
    const float* ca_w1  = (const float*)d_in[23];
    const float* ca_b1  = (const float*)d_in[24];
    const float* ca_w2  = (const float*)d_in[25];
    const float* ca_b2  = (const float*)d_in[26];

    float* ws = (float*)d_ws;
    float* xs     = ws + OFF_XS;
    float* zbuf   = ws + OFF_Z;
    float* xcm    = ws + OFF_XCM;
    float* xn     = ws + OFF_XN;
    float* dtraw  = ws + OFF_DTRAW;
    float* Bb     = ws + OFF_BB;
    float* Cb     = ws + OFF_CB;
    float* xafter = ws + OFF_XAFTER;
    float* y2     = ws + OFF_Y2;
    float* t1     = ws + OFF_T1;
    float* t2     = ws + OFF_T2;
    float* mv     = ws + OFF_MV;   // [0..95]=means, [96..191]=v2
    float* acc    = xcm;           // reuse
    float* ybuf   = xn;            // reuse

    float* out = (float*)d_out;
    const int B256 = 256;
    #define GRID(n) dim3((unsigned)(((n) + B256 - 1) / B256)), dim3(B256)

    hipLaunchKernelGGL(k_ln1,    GRID(LL),            0, stream, inp, ln1_w, ln1_b, xn);
    hipLaunchKernelGGL(k_inproj, GRID(LL * 2 * DINc), 0, stream, xn, inpj, xcm, zbuf);
    hipLaunchKernelGGL(k_dwconv, GRID(DINc * LL),     0, stream, xcm, conv_w, conv_b, xs);
    hipLaunchKernelGGL(k_perm,   GRID(7 * DINc * LL), 0, stream, xs);
    hipLaunchKernelGGL(k_xdbl,   GRID(KK * 38 * LL),  0, stream, xs, xpw, dtraw, Bb, Cb);
    hipLaunchKernelGGL(k_scan,   GRID(KK * DINc * NN),0, stream, xs, dtraw, Bb, Cb, A_logs, dt_w, dt_b, Ds);
    hipLaunchKernelGGL(k_combine,GRID(LL * DINc),     0, stream, xs, acc);
    hipLaunchKernelGGL(k_outnorm,GRID(LL),            0, stream, acc, zbuf, onw, onb, ybuf);
    hipLaunchKernelGGL(k_outproj,GRID(LL * CC),       0, stream, ybuf, opw, inp, skip1, xafter);
    hipLaunchKernelGGL(k_ln2,    GRID(LL),            0, stream, xafter, ln2_w, ln2_b, y2);
    hipLaunchKernelGGL(k_conv1,  GRID(32 * LL),       0, stream, y2, cab_w1, cab_b1, t1);
    hipLaunchKernelGGL(k_conv2,  GRID(96 * LL),       0, stream, t1, cab_w2, cab_b2, t2);
    hipLaunchKernelGGL(k_mean,   dim3(96), dim3(256), 0, stream, t2, mv);
    hipLaunchKernelGGL(k_mlp,    dim3(1), dim3(128),  0, stream, mv, ca_w1, ca_b1, ca_w2, ca_b2, mv + 96);
    hipLaunchKernelGGL(k_final,  GRID(LL * CC),       0, stream, xafter, skip2, t2, mv + 96, out);
    #undef GRID
}

// Round 2
// 2070.545 us; speedup vs baseline: 3.2590x; 3.2590x over previous
//
#include <hip/hip_runtime.h>
#include <math.h>

#define LL 8192
#define CC 96
#define DINc 96
#define NN 16
#define RR 6
#define KK 8
#define Dd 16
#define Hh 16
#define Ww 32
#define NCH 32
#define CHL 256   // LL / NCH

__constant__ int Pc_[4][3] = {{0,1,2},{1,2,0},{2,0,1},{2,1,0}};

__device__ __forceinline__ float silu_(float x){ return x / (1.f + __expf(-x)); }

// ---------------- K1: LN over C at each l ----------------
__global__ void k_ln1(const float* __restrict__ inp, const float* __restrict__ w,
                      const float* __restrict__ b, float* __restrict__ xn) {
    int l = blockIdx.x * blockDim.x + threadIdx.x;
    if (l >= LL) return;
    const float* p = inp + l * CC;
    float m = 0.f;
    for (int c = 0; c < CC; ++c) m += p[c];
    m *= (1.f / CC);
    float v = 0.f;
    for (int c = 0; c < CC; ++c) { float d = p[c] - m; v += d * d; }
    v *= (1.f / CC);
    float r = rsqrtf(v + 1e-6f);
    float* o = xn + l * CC;
    for (int c = 0; c < CC; ++c) o[c] = (p[c] - m) * r * w[c] + b[c];
}

// ---------------- K2: in_proj ----------------
__global__ void k_inproj(const float* __restrict__ xn, const float* __restrict__ W,
                         float* __restrict__ xcm, float* __restrict__ z) {
    int idx = blockIdx.x * blockDim.x + threadIdx.x;
    if (idx >= LL * 2 * DINc) return;
    int e = idx % (2 * DINc);
    int l = idx / (2 * DINc);
    const float* xr = xn + l * CC;
    const float* wr = W + e * CC;
    float s = 0.f;
    for (int c = 0; c < CC; ++c) s += xr[c] * wr[c];
    if (e < DINc) xcm[e * LL + l] = s;
    else          z[l * DINc + (e - DINc)] = s;
}

// ---------------- K3: depthwise conv3d + SiLU -> xs[0] ----------------
__global__ void k_dwconv(const float* __restrict__ xcm, const float* __restrict__ cw,
                         const float* __restrict__ cb, float* __restrict__ xs0) {
    int idx = blockIdx.x * blockDim.x + threadIdx.x;
    if (idx >= DINc * LL) return;
    int l = idx & (LL - 1);
    int c = idx >> 13;
    int w = l & (Ww - 1);
    int h = (l >> 5) & (Hh - 1);
    int d = l >> 9;
    float s = cb[c];
    const float* xp = xcm + c * LL;
    const float* wp = cw + c * 27;
    for (int kd = -1; kd <= 1; ++kd) {
        int dd = d + kd; if (dd < 0 || dd >= Dd) continue;
        for (int kh = -1; kh <= 1; ++kh) {
            int hh = h + kh; if (hh < 0 || hh >= Hh) continue;
            for (int kw = -1; kw <= 1; ++kw) {
                int ww2 = w + kw; if (ww2 < 0 || ww2 >= Ww) continue;
                s += xp[(dd * Hh + hh) * Ww + ww2] * wp[(kd + 1) * 9 + (kh + 1) * 3 + (kw + 1)];
            }
        }
    }
    xs0[c * LL + l] = silu_(s);
}

// ---------------- K4: build xs[1..7] ----------------
__global__ void k_perm(float* __restrict__ xs) {
    int idx = blockIdx.x * blockDim.x + threadIdx.x;
    if (idx >= 7 * DINc * LL) return;
    int l = idx & (LL - 1);
    int c = (idx >> 13) % DINc;
    int k = idx / (DINc * LL) + 1;
    int i  = (k < 4) ? k : (k - 4);
    int lp = (k < 4) ? l : (LL - 1 - l);
    int p0 = Pc_[i][0], p1 = Pc_[i][1], p2 = Pc_[i][2];
    const int sp[3] = {Dd, Hh, Ww};
    int pd1 = sp[p1], pd2 = sp[p2];
    int i2 = lp % pd2;
    int t  = lp / pd2;
    int i1 = t % pd1;
    int i0 = t / pd1;
    int coord[3];
    coord[p0] = i0; coord[p1] = i1; coord[p2] = i2;
    int o = (coord[0] * Hh + coord[1]) * Ww + coord[2];
    xs[(k * DINc + c) * LL + l] = xs[c * LL + o];
}

// ---------------- K5: x_dbl split ----------------
__global__ void k_xdbl(const float* __restrict__ xs, const float* __restrict__ xpw,
                       float* __restrict__ dtraw, float* __restrict__ Bb, float* __restrict__ Cb) {
    long idx = (long)blockIdx.x * blockDim.x + threadIdx.x;
    if (idx >= (long)KK * 38 * LL) return;
    int l  = idx % LL;
    int ke = idx / LL;
    int e  = ke % 38;
    int k  = ke / 38;
    const float* wp = xpw + (k * 38 + e) * DINc;
    const float* xb = xs + (long)k * DINc * LL + l;
    float s = 0.f;
    for (int d = 0; d < DINc; ++d) s += xb[d * LL] * wp[d];
    if (e < RR)            dtraw[(k * RR + e) * LL + l] = s;
    else if (e < RR + NN)  Bb[(k * NN + (e - RR)) * LL + l] = s;
    else                   Cb[(k * NN + (e - RR - NN)) * LL + l] = s;
}

// ---------------- softplus helper ----------------
__device__ __forceinline__ float softplus_(float x) {
    return (x > 20.f) ? x : __logf(1.f + __expf(x));
}

// ---------------- K7a: chunk-local scan -> (Aprod, Bacc) ----------------
// thread t: n = t&15, gc = t>>4, grp = gc>>5, chunk = gc&31
__global__ void k_scan1(const float* __restrict__ xs, const float* __restrict__ dtraw,
                        const float* __restrict__ Bb, const float* __restrict__ A_logs,
                        const float* __restrict__ dt_w, const float* __restrict__ dt_b,
                        float* __restrict__ Ap, float* __restrict__ Bc) {
    int t = blockIdx.x * blockDim.x + threadIdx.x;
    int n = t & 15;
    int gc = t >> 4;
    if (gc >= KK * DINc * NCH) return;
    int grp = gc >> 5;
    int chunk = gc & (NCH - 1);
    int k = grp / DINc;
    float A_n = -__expf(A_logs[grp * NN + n]);
    float w0 = dt_w[grp * RR + 0], w1 = dt_w[grp * RR + 1], w2 = dt_w[grp * RR + 2];
    float w3 = dt_w[grp * RR + 3], w4 = dt_w[grp * RR + 4], w5 = dt_w[grp * RR + 5];
    float dtb = dt_b[grp];
    const float* drb  = dtraw + (long)k * RR * LL + chunk * CHL;
    const float* urow = xs + (long)grp * LL + chunk * CHL;
    const float* Brow = Bb + (long)(k * NN + n) * LL + chunk * CHL;
    float hc = 0.f, dsum = 0.f;
    for (int i = 0; i < CHL; ++i) {
        float dtl = dtb + drb[i] * w0 + drb[LL + i] * w1 + drb[2 * LL + i] * w2
                        + drb[3 * LL + i] * w3 + drb[4 * LL + i] * w4 + drb[5 * LL + i] * w5;
        float dt = softplus_(dtl);
        dsum += dt;
        hc = __expf(dt * A_n) * hc + (dt * urow[i]) * Brow[i];
    }
    int o = (grp * NN + n) * NCH + chunk;
    Ap[o] = __expf(A_n * dsum);
    Bc[o] = hc;
}

// ---------------- K7b: combine chunk transfers -> start states ----------------
__global__ void k_scan2(const float* __restrict__ Ap, const float* __restrict__ Bc,
                        float* __restrict__ hs) {
    int t = blockIdx.x * blockDim.x + threadIdx.x;
    if (t >= KK * DINc * NN) return;
    int base = t * NCH;
    float h = 0.f;
    for (int c = 0; c < NCH; ++c) {
        hs[base + c] = h;
        h = Ap[base + c] * h + Bc[base + c];
    }
}

// ---------------- K7c: final chunk scan + C-reduce + y write (in-place over xs) ----------------
__global__ void k_scan3(float* __restrict__ xs_ys, const float* __restrict__ dtraw,
                        const float* __restrict__ Bb, const float* __restrict__ Cb,
                        const float* __restrict__ A_logs, const float* __restrict__ dt_w,
                        const float* __restrict__ dt_b, const float* __restrict__ Ds,
                        const float* __restrict__ hs) {
    int t = blockIdx.x * blockDim.x + threadIdx.x;
    int n = t & 15;
    int gc = t >> 4;
    if (gc >= KK * DINc * NCH) return;
    int grp = gc >> 5;
    int chunk = gc & (NCH - 1);
    int k = grp / DINc;
    float A_n = -__expf(A_logs[grp * NN + n]);
    float w0 = dt_w[grp * RR + 0], w1 = dt_w[grp * RR + 1], w2 = dt_w[grp * RR + 2];
    float w3 = dt_w[grp * RR + 3], w4 = dt_w[grp * RR + 4], w5 = dt_w[grp * RR + 5];
    float dtb = dt_b[grp];
    float Dv  = Ds[grp];
    const float* drb  = dtraw + (long)k * RR * LL + chunk * CHL;
    const float* Brow = Bb + (long)(k * NN + n) * LL + chunk * CHL;
    const float* Crow = Cb + (long)(k * NN + n) * LL + chunk * CHL;
    float* urow = xs_ys + (long)grp * LL + chunk * CHL;
    float hc = hs[(grp * NN + n) * NCH + chunk];
    for (int i = 0; i < CHL; ++i) {
        float dtl = dtb + drb[i] * w0 + drb[LL + i] * w1 + drb[2 * LL + i] * w2
                        + drb[3 * LL + i] * w3 + drb[4 * LL + i] * w4 + drb[5 * LL + i] * w5;
        float dt = softplus_(dtl);
        float u  = urow[i];
        hc = __expf(dt * A_n) * hc + (dt * u) * Brow[i];
        float yv = hc * Crow[i];
        yv += __shfl_xor(yv, 1, 16);
        yv += __shfl_xor(yv, 2, 16);
        yv += __shfl_xor(yv, 4, 16);
        yv += __shfl_xor(yv, 8, 16);
        if (n == 0) urow[i] = yv + Dv * u;
    }
}

// ---------------- K8: inverse-permute + sum 8 directions ----------------
__global__ void k_combine(const float* __restrict__ ys, float* __restrict__ acc) {
    int idx = blockIdx.x * blockDim.x + threadIdx.x;
    if (idx >= LL * DINc) return;
    int c = idx % DINc;
    int l = idx / DINc;
    int w = l & (Ww - 1);
    int h = (l >> 5) & (Hh - 1);
    int d = l >> 9;
    int coord[3] = {d, h, w};
    const int sp[3] = {Dd, Hh, Ww};
    float s = 0.f;
    #pragma unroll
    for (int i = 0; i < 4; ++i) {
        int p0 = Pc_[i][0], p1 = Pc_[i][1], p2 = Pc_[i][2];
        int lp = (coord[p0] * sp[p1] + coord[p1]) * sp[p2] + coord[p2];
        s += ys[(long)(i * DINc + c) * LL + lp];
        s += ys[(long)((4 + i) * DINc + c) * LL + (LL - 1 - lp)];
    }
    acc[l * DINc + c] = s;
}

// ---------------- K9: out_norm LN * silu(z) ----------------
__global__ void k_outnorm(const float* __restrict__ acc, const float* __restrict__ z,
                          const float* __restrict__ w, const float* __restrict__ b,
                          float* __restrict__ y) {
    int l = blockIdx.x * blockDim.x + threadIdx.x;
    if (l >= LL) return;
    const float* a = acc + l * DINc;
    float m = 0.f;
    for (int c = 0; c < DINc; ++c) m += a[c];
    m *= (1.f / DINc);
    float v = 0.f;
    for (int c = 0; c < DINc; ++c) { float d = a[c] - m; v += d * d; }
    v *= (1.f / DINc);
    float r = rsqrtf(v + 1e-5f);
    for (int c = 0; c < DINc; ++c) {
        float zz = z[l * DINc + c];
        y[l * DINc + c] = ((a[c] - m) * r * w[c] + b[c]) * silu_(zz);
    }
}

// ---------------- K10: out_proj + skip1 ----------------
__global__ void k_outproj(const float* __restrict__ y, const float* __restrict__ opw,
                          const float* __restrict__ inp, const float* __restrict__ skip1,
                          float* __restrict__ xafter) {
    int idx = blockIdx.x * blockDim.x + threadIdx.x;
    if (idx >= LL * CC) return;
    int c = idx % CC;
    int l = idx / CC;
    const float* yr = y + l * DINc;
    const float* wr = opw + c * DINc;
    float s = 0.f;
    for (int e = 0; e < DINc; ++e) s += yr[e] * wr[e];
    xafter[l * CC + c] = inp[l * CC + c] * skip1[c] + s;
}

// ---------------- K11: LN2 -> channel-major ----------------
__global__ void k_ln2(const float* __restrict__ xafter, const float* __restrict__ w,
                      const float* __restrict__ b, float* __restrict__ y2) {
    int l = blockIdx.x * blockDim.x + threadIdx.x;
    if (l >= LL) return;
    const float* p = xafter + l * CC;
    float m = 0.f;
    for (int c = 0; c < CC; ++c) m += p[c];
    m *= (1.f / CC);
    float v = 0.f;
    for (int c = 0; c < CC; ++c) { float d = p[c] - m; v += d * d; }
    v *= (1.f / CC);
    float r = rsqrtf(v + 1e-5f);
    for (int c = 0; c < CC; ++c) y2[c * LL + l] = (p[c] - m) * r * w[c] + b[c];
}

// ---------------- K12: conv3d 96->32 + GELU ----------------
__global__ void k_conv1(const float* __restrict__ y2, const float* __restrict__ w1,
                        const float* __restrict__ b1, float* __restrict__ t1) {
    int idx = blockIdx.x * blockDim.x + threadIdx.x;
    if (idx >= 32 * LL) return;
    int l = idx & (LL - 1);
    int oc = idx >> 13;
    int w = l & (Ww - 1);
    int h = (l >> 5) & (Hh - 1);
    int d = l >> 9;
    float s = b1[oc];
    for (int kd = -1; kd <= 1; ++kd) {
        int dd = d + kd; if (dd < 0 || dd >= Dd) continue;
        for (int kh = -1; kh <= 1; ++kh) {
            int hh = h + kh; if (hh < 0 || hh >= Hh) continue;
            for (int kw = -1; kw <= 1; ++kw) {
                int ww2 = w + kw; if (ww2 < 0 || ww2 >= Ww) continue;
                int nl  = (dd * Hh + hh) * Ww + ww2;
                int tap = (kd + 1) * 9 + (kh + 1) * 3 + (kw + 1);
                const float* wp = w1 + oc * 96 * 27 + tap;
                const float* xp = y2 + nl;
                float a = 0.f;
                for (int ic = 0; ic < 96; ++ic) a += xp[ic * LL] * wp[ic * 27];
                s += a;
            }
        }
    }
    t1[oc * LL + l] = 0.5f * s * (1.f + erff(s * 0.70710678118654752f));
}

// ---------------- K13: conv3d 32->96 ----------------
__global__ void k_conv2(const float* __restrict__ t1, const float* __restrict__ w2,
                        const float* __restrict__ b2, float* __restrict__ t2) {
    int idx = blockIdx.x * blockDim.x + threadIdx.x;
    if (idx >= 96 * LL) return;
    int l = idx & (LL - 1);
    int oc = idx >> 13;
    int w = l & (Ww - 1);
    int h = (l >> 5) & (Hh - 1);
    int d = l >> 9;
    float s = b2[oc];
    for (int kd = -1; kd <= 1; ++kd) {
        int dd = d + kd; if (dd < 0 || dd >= Dd) continue;
        for (int kh = -1; kh <= 1; ++kh) {
            int hh = h + kh; if (hh < 0 || hh >= Hh) continue;
            for (int kw = -1; kw <= 1; ++kw) {
                int ww2 = w + kw; if (ww2 < 0 || ww2 >= Ww) continue;
                int nl  = (dd * Hh + hh) * Ww + ww2;
                int tap = (kd + 1) * 9 + (kh + 1) * 3 + (kw + 1);
                const float* wp = w2 + oc * 32 * 27 + tap;
                const float* xp = t1 + nl;
                float a = 0.f;
                for (int ic = 0; ic < 32; ++ic) a += xp[ic * LL] * wp[ic * 27];
                s += a;
            }
        }
    }
    t2[oc * LL + l] = s;
}

// ---------------- K14a: per-channel mean ----------------
__global__ void k_mean(const float* __restrict__ t2, float* __restrict__ mbuf) {
    __shared__ float sm[256];
    int c = blockIdx.x;
    float a = 0.f;
    for (int l = threadIdx.x; l < LL; l += 256) a += t2[c * LL + l];
    sm[threadIdx.x] = a;
    __syncthreads();
    for (int o = 128; o > 0; o >>= 1) {
        if (threadIdx.x < o) sm[threadIdx.x] += sm[threadIdx.x + o];
        __syncthreads();
    }
    if (threadIdx.x == 0) mbuf[c] = sm[0] * (1.f / LL);
}

// ---------------- K14b: channel-attention MLP ----------------
__global__ void k_mlp(const float* __restrict__ mbuf, const float* __restrict__ w1,
                      const float* __restrict__ b1, const float* __restrict__ w2,
                      const float* __restrict__ b2, float* __restrict__ v2) {
    __shared__ float v[48];
    int t = threadIdx.x;
    if (t < 48) {
        float s = b1[t];
        for (int c = 0; c < 96; ++c) s += mbuf[c] * w1[t * 96 + c];
        v[t] = fmaxf(s, 0.f);
    }
    __syncthreads();
    if (t < 96) {
        float s = b2[t];
        for (int j = 0; j < 48; ++j) s += v[j] * w2[t * 48 + j];
        v2[t] = 1.f / (1.f + __expf(-s));
    }
}

// ---------------- K15: final residual ----------------
__global__ void k_final(const float* __restrict__ xafter, const float* __restrict__ skip2,
                        const float* __restrict__ t2, const float* __restrict__ v2,
                        float* __restrict__ out) {
    int idx = blockIdx.x * blockDim.x + threadIdx.x;
    if (idx >= LL * CC) return;
    int c = idx % CC;
    int l = idx / CC;
    out[l * CC + c] = xafter[l * CC + c] * skip2[c] + t2[c * LL + l] * v2[c];
}

// ---------------- workspace layout (float offsets) ----------------
static const size_t OFF_XS     = 0;          // 8*96*8192 (xs -> ys in place)
static const size_t OFF_Z      = 6291456;    // 786432
static const size_t OFF_XCM    = 7077888;    // 786432 (pre-conv x; reused as acc)
static const size_t OFF_XN     = 7864320;    // 786432 (xn; reused as y)
static const size_t OFF_DTRAW  = 8650752;    // 393216
static const size_t OFF_BB     = 9043968;    // 1048576
static const size_t OFF_CB     = 10092544;   // 1048576
static const size_t OFF_XAFTER = 11141120;   // 786432 (scan: Ap reuses this)
static const size_t OFF_Y2     = 11927552;   // 786432 (scan: Bc reuses this)
static const size_t OFF_T1     = 12713984;   // 262144
static const size_t OFF_T2     = 12976128;   // 786432 (scan: hs reuses this)
static const size_t OFF_MV     = 13762560;   // small

extern "C" void kernel_launch(void* const* d_in, const int* in_sizes, int n_in,
                              void* d_out, int out_size, void* d_ws, size_t ws_size,
                              hipStream_t stream) {
    const float* inp    = (const float*)d_in[0];
    const float* ln1_w  = (const float*)d_in[2];
    const float* ln1_b  = (const float*)d_in[3];
    const float* skip1  = (const float*)d_in[4];
    const float* skip2  = (const float*)d_in[5];
    const float* ln2_w  = (const float*)d_in[6];
    const float* ln2_b  = (const float*)d_in[7];
    const float* inpj   = (const float*)d_in[8];
    const float* conv_w = (const float*)d_in[9];
    const float* conv_b = (const float*)d_in[10];
    const float* xpw    = (const float*)d_in[11];
    const float* dt_w   = (const float*)d_in[12];
    const float* dt_b   = (const float*)d_in[13];
    const float* A_logs = (const float*)d_in[14];
    const float* Ds     = (const float*)d_in[15];
    const float* onw    = (const float*)d_in[16];
    const float* onb    = (const float*)d_in[17];
    const float* opw    = (const float*)d_in[18];
    const float* cab_w1 = (const float*)d_in[19];
    const float* cab_b1 = (const float*)d_in[20];
    const float* cab_w2 = (const float*)d_in[21];
    const float* cab_b2 = (const float*)d_in[22];
    const float* ca_w1  = (const float*)d_in[23];
    const float* ca_b1  = (const float*)d_in[24];
    const float* ca_w2  = (const float*)d_in[25];
    const float* ca_b2  = (const float*)d_in[26];

    float* ws = (float*)d_ws;
    float* xs     = ws + OFF_XS;
    float* zbuf   = ws + OFF_Z;
    float* xcm    = ws + OFF_XCM;
    float* xn     = ws + OFF_XN;
    float* dtraw  = ws + OFF_DTRAW;
    float* Bb     = ws + OFF_BB;
    float* Cb     = ws + OFF_CB;
    float* xafter = ws + OFF_XAFTER;
    float* y2     = ws + OFF_Y2;
    float* t1     = ws + OFF_T1;
    float* t2     = ws + OFF_T2;
    float* mv     = ws + OFF_MV;
    float* acc    = xcm;       // reuse (xcm dead after dwconv)
    float* ybuf   = xn;        // reuse (xn dead after inproj)
    float* Ap     = xafter;    // reuse (xafter written later at k_outproj)
    float* Bc     = y2;        // reuse (y2 written later at k_ln2)
    float* hst    = t2;        // reuse (t2 written later at k_conv2)

    float* out = (float*)d_out;
    const int B256 = 256;
    #define GRID(n) dim3((unsigned)(((n) + B256 - 1) / B256)), dim3(B256)

    hipLaunchKernelGGL(k_ln1,    GRID(LL),                 0, stream, inp, ln1_w, ln1_b, xn);
    hipLaunchKernelGGL(k_inproj, GRID(LL * 2 * DINc),      0, stream, xn, inpj, xcm, zbuf);
    hipLaunchKernelGGL(k_dwconv, GRID(DINc * LL),          0, stream, xcm, conv_w, conv_b, xs);
    hipLaunchKernelGGL(k_perm,   GRID(7 * DINc * LL),      0, stream, xs);
    hipLaunchKernelGGL(k_xdbl,   GRID(KK * 38 * LL),       0, stream, xs, xpw, dtraw, Bb, Cb);
    hipLaunchKernelGGL(k_scan1,  GRID(KK * DINc * NCH * NN), 0, stream, xs, dtraw, Bb, A_logs, dt_w, dt_b, Ap, Bc);
    hipLaunchKernelGGL(k_scan2,  GRID(KK * DINc * NN),     0, stream, Ap, Bc, hst);
    hipLaunchKernelGGL(k_scan3,  GRID(KK * DINc * NCH * NN), 0, stream, xs, dtraw, Bb, Cb, A_logs, dt_w, dt_b, Ds, hst);
    hipLaunchKernelGGL(k_combine,GRID(LL * DINc),          0, stream, xs, acc);
    hipLaunchKernelGGL(k_outnorm,GRID(LL),                 0, stream, acc, zbuf, onw, onb, ybuf);
    hipLaunchKernelGGL(k_outproj,GRID(LL * CC),            0, stream, ybuf, opw, inp, skip1, xafter);
    hipLaunchKernelGGL(k_ln2,    GRID(LL),                 0, stream, xafter, ln2_w, ln2_b, y2);
    hipLaunchKernelGGL(k_conv1,  GRID(32 * LL),            0, stream, y2, cab_w1, cab_b1, t1);
    hipLaunchKernelGGL(k_conv2,  GRID(96 * LL),            0, stream, t1, cab_w2, cab_b2, t2);
    hipLaunchKernelGGL(k_mean,   dim3(96), dim3(256),      0, stream, t2, mv);
    hipLaunchKernelGGL(k_mlp,    dim3(1), dim3(128),       0, stream, mv, ca_w1, ca_b1, ca_w2, ca_b2, mv + 96);
    hipLaunchKernelGGL(k_final,  GRID(LL * CC),            0, stream, xafter, skip2, t2, mv + 96, out);
    #undef GRID
}

// Round 3
// 1049.106 us; speedup vs baseline: 6.4321x; 1.9736x over previous
//
#include <hip/hip_runtime.h>
#include <math.h>

#define LL 8192
#define CC 96
#define DINc 96
#define NN 16
#define RR 6
#define KK 8
#define Dd 16
#define Hh 16
#define Ww 32
#define NCH 32
#define CHL 256   // LL / NCH

__constant__ int Pc_[4][3] = {{0,1,2},{1,2,0},{2,0,1},{2,1,0}};

__device__ __forceinline__ float silu_(float x){ return x / (1.f + __expf(-x)); }

// ---------------- K1: LN over C at each l ----------------
__global__ void k_ln1(const float* __restrict__ inp, const float* __restrict__ w,
                      const float* __restrict__ b, float* __restrict__ xn) {
    int l = blockIdx.x * blockDim.x + threadIdx.x;
    if (l >= LL) return;
    const float* p = inp + l * CC;
    float m = 0.f;
    for (int c = 0; c < CC; ++c) m += p[c];
    m *= (1.f / CC);
    float v = 0.f;
    for (int c = 0; c < CC; ++c) { float d = p[c] - m; v += d * d; }
    v *= (1.f / CC);
    float r = rsqrtf(v + 1e-6f);
    float* o = xn + l * CC;
    for (int c = 0; c < CC; ++c) o[c] = (p[c] - m) * r * w[c] + b[c];
}

// ---------------- K2: in_proj ----------------
__global__ void k_inproj(const float* __restrict__ xn, const float* __restrict__ W,
                         float* __restrict__ xcm, float* __restrict__ z) {
    int idx = blockIdx.x * blockDim.x + threadIdx.x;
    if (idx >= LL * 2 * DINc) return;
    int e = idx % (2 * DINc);
    int l = idx / (2 * DINc);
    const float* xr = xn + l * CC;
    const float* wr = W + e * CC;
    float s = 0.f;
    for (int c = 0; c < CC; ++c) s += xr[c] * wr[c];
    if (e < DINc) xcm[e * LL + l] = s;
    else          z[l * DINc + (e - DINc)] = s;
}

// ---------------- K3: depthwise conv3d + SiLU -> xs[0] ----------------
__global__ void k_dwconv(const float* __restrict__ xcm, const float* __restrict__ cw,
                         const float* __restrict__ cb, float* __restrict__ xs0) {
    int idx = blockIdx.x * blockDim.x + threadIdx.x;
    if (idx >= DINc * LL) return;
    int l = idx & (LL - 1);
    int c = idx >> 13;
    int w = l & (Ww - 1);
    int h = (l >> 5) & (Hh - 1);
    int d = l >> 9;
    float s = cb[c];
    const float* xp = xcm + c * LL;
    const float* wp = cw + c * 27;
    for (int kd = -1; kd <= 1; ++kd) {
        int dd = d + kd; if (dd < 0 || dd >= Dd) continue;
        for (int kh = -1; kh <= 1; ++kh) {
            int hh = h + kh; if (hh < 0 || hh >= Hh) continue;
            for (int kw = -1; kw <= 1; ++kw) {
                int ww2 = w + kw; if (ww2 < 0 || ww2 >= Ww) continue;
                s += xp[(dd * Hh + hh) * Ww + ww2] * wp[(kd + 1) * 9 + (kh + 1) * 3 + (kw + 1)];
            }
        }
    }
    xs0[c * LL + l] = silu_(s);
}

// ---------------- K4: build xs[1..7] ----------------
__global__ void k_perm(float* __restrict__ xs) {
    int idx = blockIdx.x * blockDim.x + threadIdx.x;
    if (idx >= 7 * DINc * LL) return;
    int l = idx & (LL - 1);
    int c = (idx >> 13) % DINc;
    int k = idx / (DINc * LL) + 1;
    int i  = (k < 4) ? k : (k - 4);
    int lp = (k < 4) ? l : (LL - 1 - l);
    int p0 = Pc_[i][0], p1 = Pc_[i][1], p2 = Pc_[i][2];
    const int sp[3] = {Dd, Hh, Ww};
    int pd1 = sp[p1], pd2 = sp[p2];
    int i2 = lp % pd2;
    int t  = lp / pd2;
    int i1 = t % pd1;
    int i0 = t / pd1;
    int coord[3];
    coord[p0] = i0; coord[p1] = i1; coord[p2] = i2;
    int o = (coord[0] * Hh + coord[1]) * Ww + coord[2];
    xs[(k * DINc + c) * LL + l] = xs[c * LL + o];
}

// ---------------- K5: x_dbl split; B/C stored as [k][l][n] ----------------
__global__ void k_xdbl(const float* __restrict__ xs, const float* __restrict__ xpw,
                       float* __restrict__ dtraw, float* __restrict__ Bb, float* __restrict__ Cb) {
    long idx = (long)blockIdx.x * blockDim.x + threadIdx.x;
    if (idx >= (long)KK * 38 * LL) return;
    int l  = idx % LL;
    int ke = idx / LL;
    int e  = ke % 38;
    int k  = ke / 38;
    const float* wp = xpw + (k * 38 + e) * DINc;
    const float* xb = xs + (long)k * DINc * LL + l;
    float s = 0.f;
    for (int d = 0; d < DINc; ++d) s += xb[d * LL] * wp[d];
    if (e < RR)            dtraw[(k * RR + e) * LL + l] = s;
    else if (e < RR + NN)  Bb[((long)k * LL + l) * NN + (e - RR)] = s;
    else                   Cb[((long)k * LL + l) * NN + (e - RR - NN)] = s;
}

// ---------------- softplus ----------------
__device__ __forceinline__ float softplus_(float x) {
    return (x > 20.f) ? x : __logf(1.f + __expf(x));
}

// ---------------- K7a: chunk-local scan -> (Aprod, Bacc) ----------------
// thread t: n = t&15, gc = t>>4, grp = gc>>5, chunk = gc&31
__global__ void k_scan1(const float* __restrict__ xs, const float* __restrict__ dtraw,
                        const float* __restrict__ Bb, const float* __restrict__ A_logs,
                        const float* __restrict__ dt_w, const float* __restrict__ dt_b,
                        float* __restrict__ Ap, float* __restrict__ Bc) {
    int t = blockIdx.x * blockDim.x + threadIdx.x;
    int n = t & 15;
    int gc = t >> 4;
    if (gc >= KK * DINc * NCH) return;
    int grp = gc >> 5;
    int chunk = gc & (NCH - 1);
    int k = grp / DINc;
    float A_n = -__expf(A_logs[grp * NN + n]);
    float w0 = dt_w[grp * RR + 0], w1 = dt_w[grp * RR + 1], w2 = dt_w[grp * RR + 2];
    float w3 = dt_w[grp * RR + 3], w4 = dt_w[grp * RR + 4], w5 = dt_w[grp * RR + 5];
    float dtb = dt_b[grp];
    const float* drb  = dtraw + (long)k * RR * LL + chunk * CHL;
    const float* urow = xs + (long)grp * LL + chunk * CHL;
    const float* Bblk = Bb + ((long)k * LL + chunk * CHL) * NN + n;
    float hc = 0.f, dsuml = 0.f;
    for (int base = 0; base < CHL; base += 16) {
        int lm = base + n;
        float dtl = dtb + drb[lm] * w0 + drb[LL + lm] * w1 + drb[2 * LL + lm] * w2
                        + drb[3 * LL + lm] * w3 + drb[4 * LL + lm] * w4 + drb[5 * LL + lm] * w5;
        float dt_lane = softplus_(dtl);
        float u_lane  = urow[lm];
        dsuml += dt_lane;
        #pragma unroll
        for (int j = 0; j < 16; ++j) {
            float dt = __shfl(dt_lane, j, 16);
            float u  = __shfl(u_lane,  j, 16);
            float a  = __expf(dt * A_n);
            hc = a * hc + (dt * u) * Bblk[(base + j) * NN];
        }
    }
    dsuml += __shfl_xor(dsuml, 1, 16);
    dsuml += __shfl_xor(dsuml, 2, 16);
    dsuml += __shfl_xor(dsuml, 4, 16);
    dsuml += __shfl_xor(dsuml, 8, 16);
    int o = (grp * NN + n) * NCH + chunk;
    Ap[o] = __expf(A_n * dsuml);
    Bc[o] = hc;
}

// ---------------- K7b: combine chunk transfers -> start states ----------------
__global__ void k_scan2(const float* __restrict__ Ap, const float* __restrict__ Bc,
                        float* __restrict__ hs) {
    int t = blockIdx.x * blockDim.x + threadIdx.x;
    if (t >= KK * DINc * NN) return;
    int base = t * NCH;
    float h = 0.f;
    for (int c = 0; c < NCH; ++c) {
        hs[base + c] = h;
        h = Ap[base + c] * h + Bc[base + c];
    }
}

// ---------------- K7c: final chunk scan + C-reduce + y write (in-place over xs) ----------------
__global__ void k_scan3(float* __restrict__ xs_ys, const float* __restrict__ dtraw,
                        const float* __restrict__ Bb, const float* __restrict__ Cb,
                        const float* __restrict__ A_logs, const float* __restrict__ dt_w,
                        const float* __restrict__ dt_b, const float* __restrict__ Ds,
                        const float* __restrict__ hs) {
    int t = blockIdx.x * blockDim.x + threadIdx.x;
    int n = t & 15;
    int gc = t >> 4;
    if (gc >= KK * DINc * NCH) return;
    int grp = gc >> 5;
    int chunk = gc & (NCH - 1);
    int k = grp / DINc;
    float A_n = -__expf(A_logs[grp * NN + n]);
    float w0 = dt_w[grp * RR + 0], w1 = dt_w[grp * RR + 1], w2 = dt_w[grp * RR + 2];
    float w3 = dt_w[grp * RR + 3], w4 = dt_w[grp * RR + 4], w5 = dt_w[grp * RR + 5];
    float dtb = dt_b[grp];
    float Dv  = Ds[grp];
    const float* drb  = dtraw + (long)k * RR * LL + chunk * CHL;
    const float* Bblk = Bb + ((long)k * LL + chunk * CHL) * NN + n;
    const float* Cblk = Cb + ((long)k * LL + chunk * CHL) * NN + n;
    float* urow = xs_ys + (long)grp * LL + chunk * CHL;
    float hc = hs[(grp * NN + n) * NCH + chunk];
    for (int base = 0; base < CHL; base += 16) {
        int lm = base + n;
        float dtl = dtb + drb[lm] * w0 + drb[LL + lm] * w1 + drb[2 * LL + lm] * w2
                        + drb[3 * LL + lm] * w3 + drb[4 * LL + lm] * w4 + drb[5 * LL + lm] * w5;
        float dt_lane = softplus_(dtl);
        float u_lane  = urow[lm];
        float yreg = 0.f;
        #pragma unroll
        for (int j = 0; j < 16; ++j) {
            float dt = __shfl(dt_lane, j, 16);
            float u  = __shfl(u_lane,  j, 16);
            float a  = __expf(dt * A_n);
            hc = a * hc + (dt * u) * Bblk[(base + j) * NN];
            float yv = hc * Cblk[(base + j) * NN];
            yv += __shfl_xor(yv, 1, 16);
            yv += __shfl_xor(yv, 2, 16);
            yv += __shfl_xor(yv, 4, 16);
            yv += __shfl_xor(yv, 8, 16);
            if (n == j) yreg = yv + Dv * u_lane;
        }
        urow[base + n] = yreg;
    }
}

// ---------------- K8: inverse-permute + sum 8 directions ----------------
__global__ void k_combine(const float* __restrict__ ys, float* __restrict__ acc) {
    int idx = blockIdx.x * blockDim.x + threadIdx.x;
    if (idx >= LL * DINc) return;
    int c = idx % DINc;
    int l = idx / DINc;
    int w = l & (Ww - 1);
    int h = (l >> 5) & (Hh - 1);
    int d = l >> 9;
    int coord[3] = {d, h, w};
    const int sp[3] = {Dd, Hh, Ww};
    float s = 0.f;
    #pragma unroll
    for (int i = 0; i < 4; ++i) {
        int p0 = Pc_[i][0], p1 = Pc_[i][1], p2 = Pc_[i][2];
        int lp = (coord[p0] * sp[p1] + coord[p1]) * sp[p2] + coord[p2];
        s += ys[(long)(i * DINc + c) * LL + lp];
        s += ys[(long)((4 + i) * DINc + c) * LL + (LL - 1 - lp)];
    }
    acc[l * DINc + c] = s;
}

// ---------------- K9: out_norm LN * silu(z) ----------------
__global__ void k_outnorm(const float* __restrict__ acc, const float* __restrict__ z,
                          const float* __restrict__ w, const float* __restrict__ b,
                          float* __restrict__ y) {
    int l = blockIdx.x * blockDim.x + threadIdx.x;
    if (l >= LL) return;
    const float* a = acc + l * DINc;
    float m = 0.f;
    for (int c = 0; c < DINc; ++c) m += a[c];
    m *= (1.f / DINc);
    float v = 0.f;
    for (int c = 0; c < DINc; ++c) { float d = a[c] - m; v += d * d; }
    v *= (1.f / DINc);
    float r = rsqrtf(v + 1e-5f);
    for (int c = 0; c < DINc; ++c) {
        float zz = z[l * DINc + c];
        y[l * DINc + c] = ((a[c] - m) * r * w[c] + b[c]) * silu_(zz);
    }
}

// ---------------- K10: out_proj + skip1 ----------------
__global__ void k_outproj(const float* __restrict__ y, const float* __restrict__ opw,
                          const float* __restrict__ inp, const float* __restrict__ skip1,
                          float* __restrict__ xafter) {
    int idx = blockIdx.x * blockDim.x + threadIdx.x;
    if (idx >= LL * CC) return;
    int c = idx % CC;
    int l = idx / CC;
    const float* yr = y + l * DINc;
    const float* wr = opw + c * DINc;
    float s = 0.f;
    for (int e = 0; e < DINc; ++e) s += yr[e] * wr[e];
    xafter[l * CC + c] = inp[l * CC + c] * skip1[c] + s;
}

// ---------------- K11: LN2 -> channel-major ----------------
__global__ void k_ln2(const float* __restrict__ xafter, const float* __restrict__ w,
                      const float* __restrict__ b, float* __restrict__ y2) {
    int l = blockIdx.x * blockDim.x + threadIdx.x;
    if (l >= LL) return;
    const float* p = xafter + l * CC;
    float m = 0.f;
    for (int c = 0; c < CC; ++c) m += p[c];
    m *= (1.f / CC);
    float v = 0.f;
    for (int c = 0; c < CC; ++c) { float d = p[c] - m; v += d * d; }
    v *= (1.f / CC);
    float r = rsqrtf(v + 1e-5f);
    for (int c = 0; c < CC; ++c) y2[c * LL + l] = (p[c] - m) * r * w[c] + b[c];
}

// ---------------- K12: conv3d 96->32 + GELU ----------------
__global__ void k_conv1(const float* __restrict__ y2, const float* __restrict__ w1,
                        const float* __restrict__ b1, float* __restrict__ t1) {
    int idx = blockIdx.x * blockDim.x + threadIdx.x;
    if (idx >= 32 * LL) return;
    int l = idx & (LL - 1);
    int oc = idx >> 13;
    int w = l & (Ww - 1);
    int h = (l >> 5) & (Hh - 1);
    int d = l >> 9;
    float s = b1[oc];
    for (int kd = -1; kd <= 1; ++kd) {
        int dd = d + kd; if (dd < 0 || dd >= Dd) continue;
        for (int kh = -1; kh <= 1; ++kh) {
            int hh = h + kh; if (hh < 0 || hh >= Hh) continue;
            for (int kw = -1; kw <= 1; ++kw) {
                int ww2 = w + kw; if (ww2 < 0 || ww2 >= Ww) continue;
                int nl  = (dd * Hh + hh) * Ww + ww2;
                int tap = (kd + 1) * 9 + (kh + 1) * 3 + (kw + 1);
                const float* wp = w1 + oc * 96 * 27 + tap;
                const float* xp = y2 + nl;
                float a = 0.f;
                for (int ic = 0; ic < 96; ++ic) a += xp[ic * LL] * wp[ic * 27];
                s += a;
            }
        }
    }
    t1[oc * LL + l] = 0.5f * s * (1.f + erff(s * 0.70710678118654752f));
}

// ---------------- K13: conv3d 32->96 ----------------
__global__ void k_conv2(const float* __restrict__ t1, const float* __restrict__ w2,
                        const float* __restrict__ b2, float* __restrict__ t2) {
    int idx = blockIdx.x * blockDim.x + threadIdx.x;
    if (idx >= 96 * LL) return;
    int l = idx & (LL - 1);
    int oc = idx >> 13;
    int w = l & (Ww - 1);
    int h = (l >> 5) & (Hh - 1);
    int d = l >> 9;
    float s = b2[oc];
    for (int kd = -1; kd <= 1; ++kd) {
        int dd = d + kd; if (dd < 0 || dd >= Dd) continue;
        for (int kh = -1; kh <= 1; ++kh) {
            int hh = h + kh; if (hh < 0 || hh >= Hh) continue;
            for (int kw = -1; kw <= 1; ++kw) {
                int ww2 = w + kw; if (ww2 < 0 || ww2 >= Ww) continue;
                int nl  = (dd * Hh + hh) * Ww + ww2;
                int tap = (kd + 1) * 9 + (kh + 1) * 3 + (kw + 1);
                const float* wp = w2 + oc * 32 * 27 + tap;
                const float* xp = t1 + nl;
                float a = 0.f;
                for (int ic = 0; ic < 32; ++ic) a += xp[ic * LL] * wp[ic * 27];
                s += a;
            }
        }
    }
    t2[oc * LL + l] = s;
}

// ---------------- K14a: per-channel mean ----------------
__global__ void k_mean(const float* __restrict__ t2, float* __restrict__ mbuf) {
    __shared__ float sm[256];
    int c = blockIdx.x;
    float a = 0.f;
    for (int l = threadIdx.x; l < LL; l += 256) a += t2[c * LL + l];
    sm[threadIdx.x] = a;
    __syncthreads();
    for (int o = 128; o > 0; o >>= 1) {
        if (threadIdx.x < o) sm[threadIdx.x] += sm[threadIdx.x + o];
        __syncthreads();
    }
    if (threadIdx.x == 0) mbuf[c] = sm[0] * (1.f / LL);
}

// ---------------- K14b: channel-attention MLP ----------------
__global__ void k_mlp(const float* __restrict__ mbuf, const float* __restrict__ w1,
                      const float* __restrict__ b1, const float* __restrict__ w2,
                      const float* __restrict__ b2, float* __restrict__ v2) {
    __shared__ float v[48];
    int t = threadIdx.x;
    if (t < 48) {
        float s = b1[t];
        for (int c = 0; c < 96; ++c) s += mbuf[c] * w1[t * 96 + c];
        v[t] = fmaxf(s, 0.f);
    }
    __syncthreads();
    if (t < 96) {
        float s = b2[t];
        for (int j = 0; j < 48; ++j) s += v[j] * w2[t * 48 + j];
        v2[t] = 1.f / (1.f + __expf(-s));
    }
}

// ---------------- K15: final residual ----------------
__global__ void k_final(const float* __restrict__ xafter, const float* __restrict__ skip2,
                        const float* __restrict__ t2, const float* __restrict__ v2,
                        float* __restrict__ out) {
    int idx = blockIdx.x * blockDim.x + threadIdx.x;
    if (idx >= LL * CC) return;
    int c = idx % CC;
    int l = idx / CC;
    out[l * CC + c] = xafter[l * CC + c] * skip2[c] + t2[c * LL + l] * v2[c];
}

// ---------------- workspace layout (float offsets) ----------------
static const size_t OFF_XS     = 0;          // 8*96*8192 (xs -> ys in place)
static const size_t OFF_Z      = 6291456;    // 786432
static const size_t OFF_XCM    = 7077888;    // 786432 (pre-conv x; reused as acc)
static const size_t OFF_XN     = 7864320;    // 786432 (xn; reused as y)
static const size_t OFF_DTRAW  = 8650752;    // 393216
static const size_t OFF_BB     = 9043968;    // 1048576
static const size_t OFF_CB     = 10092544;   // 1048576
static const size_t OFF_XAFTER = 11141120;   // 786432 (scan: Ap reuses this)
static const size_t OFF_Y2     = 11927552;   // 786432 (scan: Bc reuses this)
static const size_t OFF_T1     = 12713984;   // 262144
static const size_t OFF_T2     = 12976128;   // 786432 (scan: hs reuses this)
static const size_t OFF_MV     = 13762560;   // small

extern "C" void kernel_launch(void* const* d_in, const int* in_sizes, int n_in,
                              void* d_out, int out_size, void* d_ws, size_t ws_size,
                              hipStream_t stream) {
    const float* inp    = (const float*)d_in[0];
    const float* ln1_w  = (const float*)d_in[2];
    const float* ln1_b  = (const float*)d_in[3];
    const float* skip1  = (const float*)d_in[4];
    const float* skip2  = (const float*)d_in[5];
    const float* ln2_w  = (const float*)d_in[6];
    const float* ln2_b  = (const float*)d_in[7];
    const float* inpj   = (const float*)d_in[8];
    const float* conv_w = (const float*)d_in[9];
    const float* conv_b = (const float*)d_in[10];
    const float* xpw    = (const float*)d_in[11];
    const float* dt_w   = (const float*)d_in[12];
    const float* dt_b   = (const float*)d_in[13];
    const float* A_logs = (const float*)d_in[14];
    const float* Ds     = (const float*)d_in[15];
    const float* onw    = (const float*)d_in[16];
    const float* onb    = (const float*)d_in[17];
    const float* opw    = (const float*)d_in[18];
    const float* cab_w1 = (const float*)d_in[19];
    const float* cab_b1 = (const float*)d_in[20];
    const float* cab_w2 = (const float*)d_in[21];
    const float* cab_b2 = (const float*)d_in[22];
    const float* ca_w1  = (const float*)d_in[23];
    const float* ca_b1  = (const float*)d_in[24];
    const float* ca_w2  = (const float*)d_in[25];
    const float* ca_b2  = (const float*)d_in[26];

    float* ws = (float*)d_ws;
    float* xs     = ws + OFF_XS;
    float* zbuf   = ws + OFF_Z;
    float* xcm    = ws + OFF_XCM;
    float* xn     = ws + OFF_XN;
    float* dtraw  = ws + OFF_DTRAW;
    float* Bb     = ws + OFF_BB;
    float* Cb     = ws + OFF_CB;
    float* xafter = ws + OFF_XAFTER;
    float* y2     = ws + OFF_Y2;
    float* t1     = ws + OFF_T1;
    float* t2     = ws + OFF_T2;
    float* mv     = ws + OFF_MV;
    float* acc    = xcm;       // reuse (xcm dead after dwconv)
    float* ybuf   = xn;        // reuse (xn dead after inproj)
    float* Ap     = xafter;    // reuse (xafter written later at k_outproj)
    float* Bc     = y2;        // reuse (y2 written later at k_ln2)
    float* hst    = t2;        // reuse (t2 written later at k_conv2)

    float* out = (float*)d_out;
    const int B256 = 256;
    #define GRID(n) dim3((unsigned)(((n) + B256 - 1) / B256)), dim3(B256)

    hipLaunchKernelGGL(k_ln1,    GRID(LL),                 0, stream, inp, ln1_w, ln1_b, xn);
    hipLaunchKernelGGL(k_inproj, GRID(LL * 2 * DINc),      0, stream, xn, inpj, xcm, zbuf);
    hipLaunchKernelGGL(k_dwconv, GRID(DINc * LL),          0, stream, xcm, conv_w, conv_b, xs);
    hipLaunchKernelGGL(k_perm,   GRID(7 * DINc * LL),      0, stream, xs);
    hipLaunchKernelGGL(k_xdbl,   GRID(KK * 38 * LL),       0, stream, xs, xpw, dtraw, Bb, Cb);
    hipLaunchKernelGGL(k_scan1,  GRID(KK * DINc * NCH * NN), 0, stream, xs, dtraw, Bb, A_logs, dt_w, dt_b, Ap, Bc);
    hipLaunchKernelGGL(k_scan2,  GRID(KK * DINc * NN),     0, stream, Ap, Bc, hst);
    hipLaunchKernelGGL(k_scan3,  GRID(KK * DINc * NCH * NN), 0, stream, xs, dtraw, Bb, Cb, A_logs, dt_w, dt_b, Ds, hst);
    hipLaunchKernelGGL(k_combine,GRID(LL * DINc),          0, stream, xs, acc);
    hipLaunchKernelGGL(k_outnorm,GRID(LL),                 0, stream, acc, zbuf, onw, onb, ybuf);
    hipLaunchKernelGGL(k_outproj,GRID(LL * CC),            0, stream, ybuf, opw, inp, skip1, xafter);
    hipLaunchKernelGGL(k_ln2,    GRID(LL),                 0, stream, xafter, ln2_w, ln2_b, y2);
    hipLaunchKernelGGL(k_conv1,  GRID(32 * LL),            0, stream, y2, cab_w1, cab_b1, t1);
    hipLaunchKernelGGL(k_conv2,  GRID(96 * LL),            0, stream, t1, cab_w2, cab_b2, t2);
    hipLaunchKernelGGL(k_mean,   dim3(96), dim3(256),      0, stream, t2, mv);
    hipLaunchKernelGGL(k_mlp,    dim3(1), dim3(128),       0, stream, mv, ca_w1, ca_b1, ca_w2, ca_b2, mv + 96);
    hipLaunchKernelGGL(k_final,  GRID(LL * CC),            0, stream, xafter, skip2, t2, mv + 96, out);
    #undef GRID
}

// Round 4
// 883.632 us; speedup vs baseline: 7.6366x; 1.1873x over previous
//
#include <hip/hip_runtime.h>
#include <math.h>

#define LL 8192
#define CC 96
#define DINc 96
#define NN 16
#define RR 6
#define KK 8
#define Dd 16
#define Hh 16
#define Ww 32
#define NCH 32
#define CHL 256   // LL / NCH

__constant__ int Pc_[4][3] = {{0,1,2},{1,2,0},{2,0,1},{2,1,0}};

__device__ __forceinline__ float silu_(float x){ return x / (1.f + __expf(-x)); }

// ---------------- K1: LN over C at each l ----------------
__global__ void k_ln1(const float* __restrict__ inp, const float* __restrict__ w,
                      const float* __restrict__ b, float* __restrict__ xn) {
    int l = blockIdx.x * blockDim.x + threadIdx.x;
    if (l >= LL) return;
    const float* p = inp + l * CC;
    float m = 0.f;
    for (int c = 0; c < CC; ++c) m += p[c];
    m *= (1.f / CC);
    float v = 0.f;
    for (int c = 0; c < CC; ++c) { float d = p[c] - m; v += d * d; }
    v *= (1.f / CC);
    float r = rsqrtf(v + 1e-6f);
    float* o = xn + l * CC;
    for (int c = 0; c < CC; ++c) o[c] = (p[c] - m) * r * w[c] + b[c];
}

// ---------------- K2: in_proj ----------------
__global__ void k_inproj(const float* __restrict__ xn, const float* __restrict__ W,
                         float* __restrict__ xcm, float* __restrict__ z) {
    int idx = blockIdx.x * blockDim.x + threadIdx.x;
    if (idx >= LL * 2 * DINc) return;
    int e = idx % (2 * DINc);
    int l = idx / (2 * DINc);
    const float* xr = xn + l * CC;
    const float* wr = W + e * CC;
    float s = 0.f;
    for (int c = 0; c < CC; ++c) s += xr[c] * wr[c];
    if (e < DINc) xcm[e * LL + l] = s;
    else          z[l * DINc + (e - DINc)] = s;
}

// ---------------- K3: depthwise conv3d + SiLU -> xs[0] ----------------
__global__ void k_dwconv(const float* __restrict__ xcm, const float* __restrict__ cw,
                         const float* __restrict__ cb, float* __restrict__ xs0) {
    int idx = blockIdx.x * blockDim.x + threadIdx.x;
    if (idx >= DINc * LL) return;
    int l = idx & (LL - 1);
    int c = idx >> 13;
    int w = l & (Ww - 1);
    int h = (l >> 5) & (Hh - 1);
    int d = l >> 9;
    float s = cb[c];
    const float* xp = xcm + c * LL;
    const float* wp = cw + c * 27;
    for (int kd = -1; kd <= 1; ++kd) {
        int dd = d + kd; if (dd < 0 || dd >= Dd) continue;
        for (int kh = -1; kh <= 1; ++kh) {
            int hh = h + kh; if (hh < 0 || hh >= Hh) continue;
            for (int kw = -1; kw <= 1; ++kw) {
                int ww2 = w + kw; if (ww2 < 0 || ww2 >= Ww) continue;
                s += xp[(dd * Hh + hh) * Ww + ww2] * wp[(kd + 1) * 9 + (kh + 1) * 3 + (kw + 1)];
            }
        }
    }
    xs0[c * LL + l] = silu_(s);
}

// ---------------- K4: build xs[1..7] ----------------
__global__ void k_perm(float* __restrict__ xs) {
    int idx = blockIdx.x * blockDim.x + threadIdx.x;
    if (idx >= 7 * DINc * LL) return;
    int l = idx & (LL - 1);
    int c = (idx >> 13) % DINc;
    int k = idx / (DINc * LL) + 1;
    int i  = (k < 4) ? k : (k - 4);
    int lp = (k < 4) ? l : (LL - 1 - l);
    int p0 = Pc_[i][0], p1 = Pc_[i][1], p2 = Pc_[i][2];
    const int sp[3] = {Dd, Hh, Ww};
    int pd1 = sp[p1], pd2 = sp[p2];
    int i2 = lp % pd2;
    int t  = lp / pd2;
    int i1 = t % pd1;
    int i0 = t / pd1;
    int coord[3];
    coord[p0] = i0; coord[p1] = i1; coord[p2] = i2;
    int o = (coord[0] * Hh + coord[1]) * Ww + coord[2];
    xs[(k * DINc + c) * LL + l] = xs[c * LL + o];
}

// ---------------- K5: x_dbl split; B/C stored as [k][l][n] ----------------
__global__ void k_xdbl(const float* __restrict__ xs, const float* __restrict__ xpw,
                       float* __restrict__ dtraw, float* __restrict__ Bb, float* __restrict__ Cb) {
    long idx = (long)blockIdx.x * blockDim.x + threadIdx.x;
    if (idx >= (long)KK * 38 * LL) return;
    int l  = idx % LL;
    int ke = idx / LL;
    int e  = ke % 38;
    int k  = ke / 38;
    const float* wp = xpw + (k * 38 + e) * DINc;
    const float* xb = xs + (long)k * DINc * LL + l;
    float s = 0.f;
    for (int d = 0; d < DINc; ++d) s += xb[d * LL] * wp[d];
    if (e < RR)            dtraw[(k * RR + e) * LL + l] = s;
    else if (e < RR + NN)  Bb[((long)k * LL + l) * NN + (e - RR)] = s;
    else                   Cb[((long)k * LL + l) * NN + (e - RR - NN)] = s;
}

// ---------------- softplus ----------------
__device__ __forceinline__ float softplus_(float x) {
    return (x > 20.f) ? x : __logf(1.f + __expf(x));
}

// ---------------- K7a: chunk-local scan -> (Aprod, Bacc) ----------------
__global__ void k_scan1(const float* __restrict__ xs, const float* __restrict__ dtraw,
                        const float* __restrict__ Bb, const float* __restrict__ A_logs,
                        const float* __restrict__ dt_w, const float* __restrict__ dt_b,
                        float* __restrict__ Ap, float* __restrict__ Bc) {
    int t = blockIdx.x * blockDim.x + threadIdx.x;
    int n = t & 15;
    int gc = t >> 4;
    if (gc >= KK * DINc * NCH) return;
    int grp = gc >> 5;
    int chunk = gc & (NCH - 1);
    int k = grp / DINc;
    float A_n = -__expf(A_logs[grp * NN + n]);
    float w0 = dt_w[grp * RR + 0], w1 = dt_w[grp * RR + 1], w2 = dt_w[grp * RR + 2];
    float w3 = dt_w[grp * RR + 3], w4 = dt_w[grp * RR + 4], w5 = dt_w[grp * RR + 5];
    float dtb = dt_b[grp];
    const float* drb  = dtraw + (long)k * RR * LL + chunk * CHL;
    const float* urow = xs + (long)grp * LL + chunk * CHL;
    const float* Bblk = Bb + ((long)k * LL + chunk * CHL) * NN + n;
    float hc = 0.f, dsuml = 0.f;
    for (int base = 0; base < CHL; base += 16) {
        int lm = base + n;
        float dtl = dtb + drb[lm] * w0 + drb[LL + lm] * w1 + drb[2 * LL + lm] * w2
                        + drb[3 * LL + lm] * w3 + drb[4 * LL + lm] * w4 + drb[5 * LL + lm] * w5;
        float dt_lane = softplus_(dtl);
        float u_lane  = urow[lm];
        dsuml += dt_lane;
        #pragma unroll
        for (int j = 0; j < 16; ++j) {
            float dt = __shfl(dt_lane, j, 16);
            float u  = __shfl(u_lane,  j, 16);
            float a  = __expf(dt * A_n);
            hc = a * hc + (dt * u) * Bblk[(base + j) * NN];
        }
    }
    dsuml += __shfl_xor(dsuml, 1, 16);
    dsuml += __shfl_xor(dsuml, 2, 16);
    dsuml += __shfl_xor(dsuml, 4, 16);
    dsuml += __shfl_xor(dsuml, 8, 16);
    int o = (grp * NN + n) * NCH + chunk;
    Ap[o] = __expf(A_n * dsuml);
    Bc[o] = hc;
}

// ---------------- K7b: combine chunk transfers ----------------
__global__ void k_scan2(const float* __restrict__ Ap, const float* __restrict__ Bc,
                        float* __restrict__ hs) {
    int t = blockIdx.x * blockDim.x + threadIdx.x;
    if (t >= KK * DINc * NN) return;
    int base = t * NCH;
    float h = 0.f;
    for (int c = 0; c < NCH; ++c) {
        hs[base + c] = h;
        h = Ap[base + c] * h + Bc[base + c];
    }
}

// ---------------- K7c: final chunk scan + y write ----------------
__global__ void k_scan3(float* __restrict__ xs_ys, const float* __restrict__ dtraw,
                        const float* __restrict__ Bb, const float* __restrict__ Cb,
                        const float* __restrict__ A_logs, const float* __restrict__ dt_w,
                        const float* __restrict__ dt_b, const float* __restrict__ Ds,
                        const float* __restrict__ hs) {
    int t = blockIdx.x * blockDim.x + threadIdx.x;
    int n = t & 15;
    int gc = t >> 4;
    if (gc >= KK * DINc * NCH) return;
    int grp = gc >> 5;
    int chunk = gc & (NCH - 1);
    int k = grp / DINc;
    float A_n = -__expf(A_logs[grp * NN + n]);
    float w0 = dt_w[grp * RR + 0], w1 = dt_w[grp * RR + 1], w2 = dt_w[grp * RR + 2];
    float w3 = dt_w[grp * RR + 3], w4 = dt_w[grp * RR + 4], w5 = dt_w[grp * RR + 5];
    float dtb = dt_b[grp];
    float Dv  = Ds[grp];
    const float* drb  = dtraw + (long)k * RR * LL + chunk * CHL;
    const float* Bblk = Bb + ((long)k * LL + chunk * CHL) * NN + n;
    const float* Cblk = Cb + ((long)k * LL + chunk * CHL) * NN + n;
    float* urow = xs_ys + (long)grp * LL + chunk * CHL;
    float hc = hs[(grp * NN + n) * NCH + chunk];
    for (int base = 0; base < CHL; base += 16) {
        int lm = base + n;
        float dtl = dtb + drb[lm] * w0 + drb[LL + lm] * w1 + drb[2 * LL + lm] * w2
                        + drb[3 * LL + lm] * w3 + drb[4 * LL + lm] * w4 + drb[5 * LL + lm] * w5;
        float dt_lane = softplus_(dtl);
        float u_lane  = urow[lm];
        float yreg = 0.f;
        #pragma unroll
        for (int j = 0; j < 16; ++j) {
            float dt = __shfl(dt_lane, j, 16);
            float u  = __shfl(u_lane,  j, 16);
            float a  = __expf(dt * A_n);
            hc = a * hc + (dt * u) * Bblk[(base + j) * NN];
            float yv = hc * Cblk[(base + j) * NN];
            yv += __shfl_xor(yv, 1, 16);
            yv += __shfl_xor(yv, 2, 16);
            yv += __shfl_xor(yv, 4, 16);
            yv += __shfl_xor(yv, 8, 16);
            if (n == j) yreg = yv + Dv * u_lane;
        }
        urow[base + n] = yreg;
    }
}

// ---------------- K8: inverse-permute + sum 8 directions ----------------
__global__ void k_combine(const float* __restrict__ ys, float* __restrict__ acc) {
    int idx = blockIdx.x * blockDim.x + threadIdx.x;
    if (idx >= LL * DINc) return;
    int c = idx % DINc;
    int l = idx / DINc;
    int w = l & (Ww - 1);
    int h = (l >> 5) & (Hh - 1);
    int d = l >> 9;
    int coord[3] = {d, h, w};
    const int sp[3] = {Dd, Hh, Ww};
    float s = 0.f;
    #pragma unroll
    for (int i = 0; i < 4; ++i) {
        int p0 = Pc_[i][0], p1 = Pc_[i][1], p2 = Pc_[i][2];
        int lp = (coord[p0] * sp[p1] + coord[p1]) * sp[p2] + coord[p2];
        s += ys[(long)(i * DINc + c) * LL + lp];
        s += ys[(long)((4 + i) * DINc + c) * LL + (LL - 1 - lp)];
    }
    acc[l * DINc + c] = s;
}

// ---------------- K9: out_norm LN * silu(z) ----------------
__global__ void k_outnorm(const float* __restrict__ acc, const float* __restrict__ z,
                          const float* __restrict__ w, const float* __restrict__ b,
                          float* __restrict__ y) {
    int l = blockIdx.x * blockDim.x + threadIdx.x;
    if (l >= LL) return;
    const float* a = acc + l * DINc;
    float m = 0.f;
    for (int c = 0; c < DINc; ++c) m += a[c];
    m *= (1.f / DINc);
    float v = 0.f;
    for (int c = 0; c < DINc; ++c) { float d = a[c] - m; v += d * d; }
    v *= (1.f / DINc);
    float r = rsqrtf(v + 1e-5f);
    for (int c = 0; c < DINc; ++c) {
        float zz = z[l * DINc + c];
        y[l * DINc + c] = ((a[c] - m) * r * w[c] + b[c]) * silu_(zz);
    }
}

// ---------------- K10: out_proj + skip1 ----------------
__global__ void k_outproj(const float* __restrict__ y, const float* __restrict__ opw,
                          const float* __restrict__ inp, const float* __restrict__ skip1,
                          float* __restrict__ xafter) {
    int idx = blockIdx.x * blockDim.x + threadIdx.x;
    if (idx >= LL * CC) return;
    int c = idx % CC;
    int l = idx / CC;
    const float* yr = y + l * DINc;
    const float* wr = opw + c * DINc;
    float s = 0.f;
    for (int e = 0; e < DINc; ++e) s += yr[e] * wr[e];
    xafter[l * CC + c] = inp[l * CC + c] * skip1[c] + s;
}

// ---------------- K11: LN2 -> channel-major ----------------
__global__ void k_ln2(const float* __restrict__ xafter, const float* __restrict__ w,
                      const float* __restrict__ b, float* __restrict__ y2) {
    int l = blockIdx.x * blockDim.x + threadIdx.x;
    if (l >= LL) return;
    const float* p = xafter + l * CC;
    float m = 0.f;
    for (int c = 0; c < CC; ++c) m += p[c];
    m *= (1.f / CC);
    float v = 0.f;
    for (int c = 0; c < CC; ++c) { float d = p[c] - m; v += d * d; }
    v *= (1.f / CC);
    float r = rsqrtf(v + 1e-5f);
    for (int c = 0; c < CC; ++c) y2[c * LL + l] = (p[c] - m) * r * w[c] + b[c];
}

// ---------------- KW: transpose conv weights -> [ic][tap][oc] ----------------
__global__ void k_wtrans(const float* __restrict__ w1, const float* __restrict__ w2,
                         float* __restrict__ wT1, float* __restrict__ wT2) {
    int idx = blockIdx.x * blockDim.x + threadIdx.x;
    if (idx >= 96 * 27 * 32) return;
    {   // wT1: [ic][tap][oc=32]
        int oc = idx & 31; int tap = (idx >> 5) % 27; int ic = idx / (32 * 27);
        wT1[idx] = w1[(oc * 96 + ic) * 27 + tap];
    }
    {   // wT2: [ic][tap][oc=96]  (same element count)
        int oc = idx % 96; int tap = (idx / 96) % 27; int ic = idx / (96 * 27);
        wT2[idx] = w2[(oc * 32 + ic) * 27 + tap];
    }
}

// ---------------- K12: conv3d 96->32, register-blocked, 4-way ic-split ----------------
// idx -> l (0..8191), g = idx>>13: ocg = g&3 (8 oc each), isp = g>>2 (24 ic each)
__global__ void k_conv1(const float* __restrict__ y2, const float* __restrict__ wT,
                        float* __restrict__ part) {
    int idx = blockIdx.x * blockDim.x + threadIdx.x;
    if (idx >= LL * 16) return;
    int l = idx & (LL - 1);
    int g = idx >> 13;
    int ocg = g & 3;
    int isp = g >> 2;
    int w = l & (Ww - 1);
    int h = (l >> 5) & (Hh - 1);
    int d = l >> 9;
    float a[8];
    #pragma unroll
    for (int j = 0; j < 8; ++j) a[j] = 0.f;
    for (int ic = isp * 24; ic < isp * 24 + 24; ++ic) {
        const float* xp = y2 + ic * LL;
        const float* wb = wT + ic * 27 * 32 + ocg * 8;
        for (int kd = -1; kd <= 1; ++kd) {
            int dd = d + kd; if ((unsigned)dd >= Dd) continue;
            for (int kh = -1; kh <= 1; ++kh) {
                int hh = h + kh; if ((unsigned)hh >= Hh) continue;
                int rowb = (dd * Hh + hh) * Ww;
                int tapb = ((kd + 1) * 9 + (kh + 1) * 3) * 32;
                #pragma unroll
                for (int kw = -1; kw <= 1; ++kw) {
                    int ww2 = w + kw; if ((unsigned)ww2 >= Ww) continue;
                    float x = xp[rowb + ww2];
                    const float4* wv = (const float4*)(wb + tapb + (kw + 1) * 32);
                    float4 wa = wv[0], wbv = wv[1];
                    a[0] += x * wa.x;  a[1] += x * wa.y;  a[2] += x * wa.z;  a[3] += x * wa.w;
                    a[4] += x * wbv.x; a[5] += x * wbv.y; a[6] += x * wbv.z; a[7] += x * wbv.w;
                }
            }
        }
    }
    float* pp = part + ((long)isp * 32 + ocg * 8) * LL + l;
    #pragma unroll
    for (int j = 0; j < 8; ++j) pp[(long)j * LL] = a[j];
}

// ---------------- K12b: t1 = GELU(sum partials + bias) ----------------
__global__ void k_gelusum(const float* __restrict__ part, const float* __restrict__ b1,
                          float* __restrict__ t1) {
    int idx = blockIdx.x * blockDim.x + threadIdx.x;
    if (idx >= 32 * LL) return;
    int l = idx & (LL - 1);
    int oc = idx >> 13;
    float s = b1[oc]
            + part[((long)0 * 32 + oc) * LL + l]
            + part[((long)1 * 32 + oc) * LL + l]
            + part[((long)2 * 32 + oc) * LL + l]
            + part[((long)3 * 32 + oc) * LL + l];
    t1[oc * LL + l] = 0.5f * s * (1.f + erff(s * 0.70710678118654752f));
}

// ---------------- K13: conv3d 32->96, register-blocked ----------------
// idx -> l, ocg = idx>>13 (0..11, 8 oc each)
__global__ void k_conv2(const float* __restrict__ t1, const float* __restrict__ wT,
                        const float* __restrict__ b2, float* __restrict__ t2) {
    int idx = blockIdx.x * blockDim.x + threadIdx.x;
    if (idx >= LL * 12) return;
    int l = idx & (LL - 1);
    int ocg = idx >> 13;
    int w = l & (Ww - 1);
    int h = (l >> 5) & (Hh - 1);
    int d = l >> 9;
    float a[8];
    #pragma unroll
    for (int j = 0; j < 8; ++j) a[j] = b2[ocg * 8 + j];
    for (int ic = 0; ic < 32; ++ic) {
        const float* xp = t1 + ic * LL;
        const float* wb = wT + ic * 27 * 96 + ocg * 8;
        for (int kd = -1; kd <= 1; ++kd) {
            int dd = d + kd; if ((unsigned)dd >= Dd) continue;
            for (int kh = -1; kh <= 1; ++kh) {
                int hh = h + kh; if ((unsigned)hh >= Hh) continue;
                int rowb = (dd * Hh + hh) * Ww;
                int tapb = ((kd + 1) * 9 + (kh + 1) * 3) * 96;
                #pragma unroll
                for (int kw = -1; kw <= 1; ++kw) {
                    int ww2 = w + kw; if ((unsigned)ww2 >= Ww) continue;
                    float x = xp[rowb + ww2];
                    const float4* wv = (const float4*)(wb + tapb + (kw + 1) * 96);
                    float4 wa = wv[0], wbv = wv[1];
                    a[0] += x * wa.x;  a[1] += x * wa.y;  a[2] += x * wa.z;  a[3] += x * wa.w;
                    a[4] += x * wbv.x; a[5] += x * wbv.y; a[6] += x * wbv.z; a[7] += x * wbv.w;
                }
            }
        }
    }
    float* pp = t2 + (long)(ocg * 8) * LL + l;
    #pragma unroll
    for (int j = 0; j < 8; ++j) pp[(long)j * LL] = a[j];
}

// ---------------- K14a: per-channel mean ----------------
__global__ void k_mean(const float* __restrict__ t2, float* __restrict__ mbuf) {
    __shared__ float sm[256];
    int c = blockIdx.x;
    float a = 0.f;
    for (int l = threadIdx.x; l < LL; l += 256) a += t2[c * LL + l];
    sm[threadIdx.x] = a;
    __syncthreads();
    for (int o = 128; o > 0; o >>= 1) {
        if (threadIdx.x < o) sm[threadIdx.x] += sm[threadIdx.x + o];
        __syncthreads();
    }
    if (threadIdx.x == 0) mbuf[c] = sm[0] * (1.f / LL);
}

// ---------------- K14b: channel-attention MLP ----------------
__global__ void k_mlp(const float* __restrict__ mbuf, const float* __restrict__ w1,
                      const float* __restrict__ b1, const float* __restrict__ w2,
                      const float* __restrict__ b2, float* __restrict__ v2) {
    __shared__ float v[48];
    int t = threadIdx.x;
    if (t < 48) {
        float s = b1[t];
        for (int c = 0; c < 96; ++c) s += mbuf[c] * w1[t * 96 + c];
        v[t] = fmaxf(s, 0.f);
    }
    __syncthreads();
    if (t < 96) {
        float s = b2[t];
        for (int j = 0; j < 48; ++j) s += v[j] * w2[t * 48 + j];
        v2[t] = 1.f / (1.f + __expf(-s));
    }
}

// ---------------- K15: final residual ----------------
__global__ void k_final(const float* __restrict__ xafter, const float* __restrict__ skip2,
                        const float* __restrict__ t2, const float* __restrict__ v2,
                        float* __restrict__ out) {
    int idx = blockIdx.x * blockDim.x + threadIdx.x;
    if (idx >= LL * CC) return;
    int c = idx % CC;
    int l = idx / CC;
    out[l * CC + c] = xafter[l * CC + c] * skip2[c] + t2[c * LL + l] * v2[c];
}

// ---------------- workspace layout (float offsets) ----------------
static const size_t OFF_XS     = 0;          // 8*96*8192 (xs -> ys in place; conv scratch after combine)
static const size_t OFF_Z      = 6291456;    // 786432
static const size_t OFF_XCM    = 7077888;    // 786432 (pre-conv x; reused as acc)
static const size_t OFF_XN     = 7864320;    // 786432 (xn; reused as y)
static const size_t OFF_DTRAW  = 8650752;    // 393216
static const size_t OFF_BB     = 9043968;    // 1048576
static const size_t OFF_CB     = 10092544;   // 1048576
static const size_t OFF_XAFTER = 11141120;   // 786432 (scan: Ap reuses this)
static const size_t OFF_Y2     = 11927552;   // 786432 (scan: Bc reuses this)
static const size_t OFF_T1     = 12713984;   // 262144
static const size_t OFF_T2     = 12976128;   // 786432 (scan: hs reuses this)
static const size_t OFF_MV     = 13762560;   // small

extern "C" void kernel_launch(void* const* d_in, const int* in_sizes, int n_in,
                              void* d_out, int out_size, void* d_ws, size_t ws_size,
                              hipStream_t stream) {
    const float* inp    = (const float*)d_in[0];
    const float* ln1_w  = (const float*)d_in[2];
    const float* ln1_b  = (const float*)d_in[3];
    const float* skip1  = (const float*)d_in[4];
    const float* skip2  = (const float*)d_in[5];
    const float* ln2_w  = (const float*)d_in[6];
    const float* ln2_b  = (const float*)d_in[7];
    const float* inpj   = (const float*)d_in[8];
    const float* conv_w = (const float*)d_in[9];
    const float* conv_b = (const float*)d_in[10];
    const float* xpw    = (const float*)d_in[11];
    const float* dt_w   = (const float*)d_in[12];
    const float* dt_b   = (const float*)d_in[13];
    const float* A_logs = (const float*)d_in[14];
    const float* Ds     = (const float*)d_in[15];
    const float* onw    = (const float*)d_in[16];
    const float* onb    = (const float*)d_in[17];
    const float* opw    = (const float*)d_in[18];
    const float* cab_w1 = (const float*)d_in[19];
    const float* cab_b1 = (const float*)d_in[20];
    const float* cab_w2 = (const float*)d_in[21];
    const float* cab_b2 = (const float*)d_in[22];
    const float* ca_w1  = (const float*)d_in[23];
    const float* ca_b1  = (const float*)d_in[24];
    const float* ca_w2  = (const float*)d_in[25];
    const float* ca_b2  = (const float*)d_in[26];

    float* ws = (float*)d_ws;
    float* xs     = ws + OFF_XS;
    float* zbuf   = ws + OFF_Z;
    float* xcm    = ws + OFF_XCM;
    float* xn     = ws + OFF_XN;
    float* dtraw  = ws + OFF_DTRAW;
    float* Bb     = ws + OFF_BB;
    float* Cb     = ws + OFF_CB;
    float* xafter = ws + OFF_XAFTER;
    float* y2     = ws + OFF_Y2;
    float* t1     = ws + OFF_T1;
    float* t2     = ws + OFF_T2;
    float* mv     = ws + OFF_MV;
    float* acc    = xcm;       // reuse (xcm dead after dwconv)
    float* ybuf   = xn;        // reuse (xn dead after inproj)
    float* Ap     = xafter;    // reuse (xafter written later at k_outproj)
    float* Bc     = y2;        // reuse (y2 written later at k_ln2)
    float* hst    = t2;        // reuse (t2 written later at k_conv2)
    // conv scratch inside the xs region (dead after k_combine):
    float* wT1    = xs;                 // 82944
    float* wT2    = xs + 82944;         // 82944
    float* part   = xs + 165888;        // 4*32*8192 = 1048576

    float* out = (float*)d_out;
    const int B256 = 256;
    #define GRID(n) dim3((unsigned)(((n) + B256 - 1) / B256)), dim3(B256)

    hipLaunchKernelGGL(k_ln1,    GRID(LL),                 0, stream, inp, ln1_w, ln1_b, xn);
    hipLaunchKernelGGL(k_inproj, GRID(LL * 2 * DINc),      0, stream, xn, inpj, xcm, zbuf);
    hipLaunchKernelGGL(k_dwconv, GRID(DINc * LL),          0, stream, xcm, conv_w, conv_b, xs);
    hipLaunchKernelGGL(k_perm,   GRID(7 * DINc * LL),      0, stream, xs);
    hipLaunchKernelGGL(k_xdbl,   GRID(KK * 38 * LL),       0, stream, xs, xpw, dtraw, Bb, Cb);
    hipLaunchKernelGGL(k_scan1,  GRID(KK * DINc * NCH * NN), 0, stream, xs, dtraw, Bb, A_logs, dt_w, dt_b, Ap, Bc);
    hipLaunchKernelGGL(k_scan2,  GRID(KK * DINc * NN),     0, stream, Ap, Bc, hst);
    hipLaunchKernelGGL(k_scan3,  GRID(KK * DINc * NCH * NN), 0, stream, xs, dtraw, Bb, Cb, A_logs, dt_w, dt_b, Ds, hst);
    hipLaunchKernelGGL(k_combine,GRID(LL * DINc),          0, stream, xs, acc);
    hipLaunchKernelGGL(k_outnorm,GRID(LL),                 0, stream, acc, zbuf, onw, onb, ybuf);
    hipLaunchKernelGGL(k_outproj,GRID(LL * CC),            0, stream, ybuf, opw, inp, skip1, xafter);
    hipLaunchKernelGGL(k_wtrans, GRID(96 * 27 * 32),       0, stream, cab_w1, cab_w2, wT1, wT2);
    hipLaunchKernelGGL(k_ln2,    GRID(LL),                 0, stream, xafter, ln2_w, ln2_b, y2);
    hipLaunchKernelGGL(k_conv1,  GRID(LL * 16),            0, stream, y2, wT1, part);
    hipLaunchKernelGGL(k_gelusum,GRID(32 * LL),            0, stream, part, cab_b1, t1);
    hipLaunchKernelGGL(k_conv2,  GRID(LL * 12),            0, stream, t1, wT2, cab_b2, t2);
    hipLaunchKernelGGL(k_mean,   dim3(96), dim3(256),      0, stream, t2, mv);
    hipLaunchKernelGGL(k_mlp,    dim3(1), dim3(128),       0, stream, mv, ca_w1, ca_b1, ca_w2, ca_b2, mv + 96);
    hipLaunchKernelGGL(k_final,  GRID(LL * CC),            0, stream, xafter, skip2, t2, mv + 96, out);
    #undef GRID
}

// Round 5
// 526.854 us; speedup vs baseline: 12.8080x; 1.6772x over previous
//
#include <hip/hip_runtime.h>
#include <math.h>

#define LL 8192
#define CC 96
#define DINc 96
#define NN 16
#define RR 6
#define KK 8
#define Dd 16
#define Hh 16
#define Ww 32
#define NCH 32
#define CHL 256   // LL / NCH

__constant__ int Pc_[4][3] = {{0,1,2},{1,2,0},{2,0,1},{2,1,0}};

__device__ __forceinline__ float silu_(float x){ return x / (1.f + __expf(-x)); }

// ---------------- K1: LN over C at each l -> xn CHANNEL-MAJOR [c][l] ----------------
__global__ void k_ln1(const float* __restrict__ inp, const float* __restrict__ w,
                      const float* __restrict__ b, float* __restrict__ xn_cm) {
    int l = blockIdx.x * blockDim.x + threadIdx.x;
    if (l >= LL) return;
    const float* p = inp + l * CC;
    float m = 0.f;
    for (int c = 0; c < CC; ++c) m += p[c];
    m *= (1.f / CC);
    float v = 0.f;
    for (int c = 0; c < CC; ++c) { float d = p[c] - m; v += d * d; }
    v *= (1.f / CC);
    float r = rsqrtf(v + 1e-6f);
    for (int c = 0; c < CC; ++c) xn_cm[c * LL + l] = (p[c] - m) * r * w[c] + b[c];
}

// ---------------- KW: transpose weights (in_proj, x_proj, cab convs) ----------------
__global__ void k_wtrans(const float* __restrict__ inpj, const float* __restrict__ xpw,
                         const float* __restrict__ w1, const float* __restrict__ w2,
                         float* __restrict__ ipT, float* __restrict__ xpT,
                         float* __restrict__ wT1, float* __restrict__ wT2) {
    int idx = blockIdx.x * blockDim.x + threadIdx.x;
    if (idx < 82944) {   // wT1: [ic][tap][oc=32]
        int oc = idx & 31; int tap = (idx >> 5) % 27; int ic = idx / (32 * 27);
        wT1[idx] = w1[(oc * 96 + ic) * 27 + tap];
    }
    if (idx < 82944) {   // wT2: [ic][tap][oc=96]
        int oc = idx % 96; int tap = (idx / 96) % 27; int ic = idx / (96 * 27);
        wT2[idx] = w2[(oc * 32 + ic) * 27 + tap];
    }
    if (idx < 18432) {   // ipT: [c][e=192]
        int e = idx % 192; int c = idx / 192;
        ipT[idx] = inpj[e * 96 + c];
    }
    if (idx < 29184) {   // xpT: [k][c][e=38]
        int e = idx % 38; int c = (idx / 38) % 96; int k = idx / (38 * 96);
        xpT[idx] = xpw[(k * 38 + e) * 96 + c];
    }
}

// ---------------- K2: in_proj, 8-e register block, uniform weights ----------------
// grid: 24 e-blocks x 32 l-blocks
__global__ void k_inproj(const float* __restrict__ xn_cm, const float* __restrict__ ipT,
                         float* __restrict__ xcm, float* __restrict__ z_cm) {
    int bx = blockIdx.x;
    int eb = bx >> 5;                       // 0..23 (uniform)
    int l  = ((bx & 31) << 8) + threadIdx.x;
    int e0 = eb << 3;
    float a[8];
    #pragma unroll
    for (int j = 0; j < 8; ++j) a[j] = 0.f;
    const float* wp = ipT + e0;
    for (int c = 0; c < CC; ++c) {
        float x = xn_cm[c * LL + l];
        const float4* wv = (const float4*)(wp + c * 192);
        float4 wa = wv[0], wb = wv[1];
        a[0] += x * wa.x; a[1] += x * wa.y; a[2] += x * wa.z; a[3] += x * wa.w;
        a[4] += x * wb.x; a[5] += x * wb.y; a[6] += x * wb.z; a[7] += x * wb.w;
    }
    float* dst = (e0 < DINc) ? (xcm + (long)e0 * LL) : (z_cm + (long)(e0 - DINc) * LL);
    #pragma unroll
    for (int j = 0; j < 8; ++j) dst[(long)j * LL + l] = a[j];
}

// ---------------- K3: depthwise conv3d + SiLU -> xs[0] ----------------
__global__ void k_dwconv(const float* __restrict__ xcm, const float* __restrict__ cw,
                         const float* __restrict__ cb, float* __restrict__ xs0) {
    int idx = blockIdx.x * blockDim.x + threadIdx.x;
    if (idx >= DINc * LL) return;
    int l = idx & (LL - 1);
    int c = idx >> 13;
    int w = l & (Ww - 1);
    int h = (l >> 5) & (Hh - 1);
    int d = l >> 9;
    float s = cb[c];
    const float* xp = xcm + c * LL;
    const float* wp = cw + c * 27;
    for (int kd = -1; kd <= 1; ++kd) {
        int dd = d + kd; if ((unsigned)dd >= Dd) continue;
        for (int kh = -1; kh <= 1; ++kh) {
            int hh = h + kh; if ((unsigned)hh >= Hh) continue;
            for (int kw = -1; kw <= 1; ++kw) {
                int ww2 = w + kw; if ((unsigned)ww2 >= Ww) continue;
                s += xp[(dd * Hh + hh) * Ww + ww2] * wp[(kd + 1) * 9 + (kh + 1) * 3 + (kw + 1)];
            }
        }
    }
    xs0[c * LL + l] = silu_(s);
}

// ---------------- K4: build xs[1..7] ----------------
__global__ void k_perm(float* __restrict__ xs) {
    int idx = blockIdx.x * blockDim.x + threadIdx.x;
    if (idx >= 7 * DINc * LL) return;
    int l = idx & (LL - 1);
    int c = (idx >> 13) % DINc;
    int k = idx / (DINc * LL) + 1;
    int i  = (k < 4) ? k : (k - 4);
    int lp = (k < 4) ? l : (LL - 1 - l);
    int p0 = Pc_[i][0], p1 = Pc_[i][1], p2 = Pc_[i][2];
    const int sp[3] = {Dd, Hh, Ww};
    int pd1 = sp[p1], pd2 = sp[p2];
    int i2 = lp % pd2;
    int t  = lp / pd2;
    int i1 = t % pd1;
    int i0 = t / pd1;
    int coord[3];
    coord[p0] = i0; coord[p1] = i1; coord[p2] = i2;
    int o = (coord[0] * Hh + coord[1]) * Ww + coord[2];
    xs[(k * DINc + c) * LL + l] = xs[c * LL + o];
}

// ---------------- K5: x_dbl, 38 accumulators per (k,l), xs read once ----------------
// grid: 8 k x 32 l-blocks
__global__ void k_xdbl(const float* __restrict__ xs, const float* __restrict__ xpT,
                       float* __restrict__ dtraw, float* __restrict__ Bb, float* __restrict__ Cb) {
    int bx = blockIdx.x;
    int k = bx >> 5;                        // uniform
    int l = ((bx & 31) << 8) + threadIdx.x;
    float acc[38];
    #pragma unroll
    for (int e = 0; e < 38; ++e) acc[e] = 0.f;
    const float* xb = xs + (long)k * DINc * LL + l;
    const float* wb = xpT + k * DINc * 38;
    for (int c = 0; c < DINc; ++c) {
        float x = xb[(long)c * LL];
        const float* wr = wb + c * 38;
        #pragma unroll
        for (int e = 0; e < 38; ++e) acc[e] += x * wr[e];
    }
    #pragma unroll
    for (int r = 0; r < RR; ++r) dtraw[(k * RR + r) * LL + l] = acc[r];
    float* Bp = Bb + ((long)k * LL + l) * NN;
    float* Cp = Cb + ((long)k * LL + l) * NN;
    #pragma unroll
    for (int n = 0; n < NN; ++n) { Bp[n] = acc[RR + n]; Cp[n] = acc[RR + NN + n]; }
}

// ---------------- softplus ----------------
__device__ __forceinline__ float softplus_(float x) {
    return (x > 20.f) ? x : __logf(1.f + __expf(x));
}

// ---------------- K7a: chunk-local scan -> (Aprod, Bacc) ----------------
__global__ void k_scan1(const float* __restrict__ xs, const float* __restrict__ dtraw,
                        const float* __restrict__ Bb, const float* __restrict__ A_logs,
                        const float* __restrict__ dt_w, const float* __restrict__ dt_b,
                        float* __restrict__ Ap, float* __restrict__ Bc) {
    int t = blockIdx.x * blockDim.x + threadIdx.x;
    int n = t & 15;
    int gc = t >> 4;
    if (gc >= KK * DINc * NCH) return;
    int grp = gc >> 5;
    int chunk = gc & (NCH - 1);
    int k = grp / DINc;
    float A_n = -__expf(A_logs[grp * NN + n]);
    float w0 = dt_w[grp * RR + 0], w1 = dt_w[grp * RR + 1], w2 = dt_w[grp * RR + 2];
    float w3 = dt_w[grp * RR + 3], w4 = dt_w[grp * RR + 4], w5 = dt_w[grp * RR + 5];
    float dtb = dt_b[grp];
    const float* drb  = dtraw + (long)k * RR * LL + chunk * CHL;
    const float* urow = xs + (long)grp * LL + chunk * CHL;
    const float* Bblk = Bb + ((long)k * LL + chunk * CHL) * NN + n;
    float hc = 0.f, dsuml = 0.f;
    for (int base = 0; base < CHL; base += 16) {
        int lm = base + n;
        float dtl = dtb + drb[lm] * w0 + drb[LL + lm] * w1 + drb[2 * LL + lm] * w2
                        + drb[3 * LL + lm] * w3 + drb[4 * LL + lm] * w4 + drb[5 * LL + lm] * w5;
        float dt_lane = softplus_(dtl);
        float u_lane  = urow[lm];
        dsuml += dt_lane;
        #pragma unroll
        for (int j = 0; j < 16; ++j) {
            float dt = __shfl(dt_lane, j, 16);
            float u  = __shfl(u_lane,  j, 16);
            float a  = __expf(dt * A_n);
            hc = a * hc + (dt * u) * Bblk[(base + j) * NN];
        }
    }
    dsuml += __shfl_xor(dsuml, 1, 16);
    dsuml += __shfl_xor(dsuml, 2, 16);
    dsuml += __shfl_xor(dsuml, 4, 16);
    dsuml += __shfl_xor(dsuml, 8, 16);
    int o = (grp * NN + n) * NCH + chunk;
    Ap[o] = __expf(A_n * dsuml);
    Bc[o] = hc;
}

// ---------------- K7b: combine chunk transfers ----------------
__global__ void k_scan2(const float* __restrict__ Ap, const float* __restrict__ Bc,
                        float* __restrict__ hs) {
    int t = blockIdx.x * blockDim.x + threadIdx.x;
    if (t >= KK * DINc * NN) return;
    int base = t * NCH;
    float h = 0.f;
    for (int c = 0; c < NCH; ++c) {
        hs[base + c] = h;
        h = Ap[base + c] * h + Bc[base + c];
    }
}

// ---------------- K7c: final chunk scan + y write ----------------
__global__ void k_scan3(float* __restrict__ xs_ys, const float* __restrict__ dtraw,
                        const float* __restrict__ Bb, const float* __restrict__ Cb,
                        const float* __restrict__ A_logs, const float* __restrict__ dt_w,
                        const float* __restrict__ dt_b, const float* __restrict__ Ds,
                        const float* __restrict__ hs) {
    int t = blockIdx.x * blockDim.x + threadIdx.x;
    int n = t & 15;
    int gc = t >> 4;
    if (gc >= KK * DINc * NCH) return;
    int grp = gc >> 5;
    int chunk = gc & (NCH - 1);
    int k = grp / DINc;
    float A_n = -__expf(A_logs[grp * NN + n]);
    float w0 = dt_w[grp * RR + 0], w1 = dt_w[grp * RR + 1], w2 = dt_w[grp * RR + 2];
    float w3 = dt_w[grp * RR + 3], w4 = dt_w[grp * RR + 4], w5 = dt_w[grp * RR + 5];
    float dtb = dt_b[grp];
    float Dv  = Ds[grp];
    const float* drb  = dtraw + (long)k * RR * LL + chunk * CHL;
    const float* Bblk = Bb + ((long)k * LL + chunk * CHL) * NN + n;
    const float* Cblk = Cb + ((long)k * LL + chunk * CHL) * NN + n;
    float* urow = xs_ys + (long)grp * LL + chunk * CHL;
    float hc = hs[(grp * NN + n) * NCH + chunk];
    for (int base = 0; base < CHL; base += 16) {
        int lm = base + n;
        float dtl = dtb + drb[lm] * w0 + drb[LL + lm] * w1 + drb[2 * LL + lm] * w2
                        + drb[3 * LL + lm] * w3 + drb[4 * LL + lm] * w4 + drb[5 * LL + lm] * w5;
        float dt_lane = softplus_(dtl);
        float u_lane  = urow[lm];
        float yreg = 0.f;
        #pragma unroll
        for (int j = 0; j < 16; ++j) {
            float dt = __shfl(dt_lane, j, 16);
            float u  = __shfl(u_lane,  j, 16);
            float a  = __expf(dt * A_n);
            hc = a * hc + (dt * u) * Bblk[(base + j) * NN];
            float yv = hc * Cblk[(base + j) * NN];
            yv += __shfl_xor(yv, 1, 16);
            yv += __shfl_xor(yv, 2, 16);
            yv += __shfl_xor(yv, 4, 16);
            yv += __shfl_xor(yv, 8, 16);
            if (n == j) yreg = yv + Dv * u_lane;
        }
        urow[base + n] = yreg;
    }
}

// ---------------- K8: inverse-permute + sum 8 directions ----------------
__global__ void k_combine(const float* __restrict__ ys, float* __restrict__ acc) {
    int idx = blockIdx.x * blockDim.x + threadIdx.x;
    if (idx >= LL * DINc) return;
    int c = idx % DINc;
    int l = idx / DINc;
    int w = l & (Ww - 1);
    int h = (l >> 5) & (Hh - 1);
    int d = l >> 9;
    int coord[3] = {d, h, w};
    const int sp[3] = {Dd, Hh, Ww};
    float s = 0.f;
    #pragma unroll
    for (int i = 0; i < 4; ++i) {
        int p0 = Pc_[i][0], p1 = Pc_[i][1], p2 = Pc_[i][2];
        int lp = (coord[p0] * sp[p1] + coord[p1]) * sp[p2] + coord[p2];
        s += ys[(long)(i * DINc + c) * LL + lp];
        s += ys[(long)((4 + i) * DINc + c) * LL + (LL - 1 - lp)];
    }
    acc[l * DINc + c] = s;
}

// ---------------- K9: out_norm LN * silu(z_cm) ----------------
__global__ void k_outnorm(const float* __restrict__ acc, const float* __restrict__ z_cm,
                          const float* __restrict__ w, const float* __restrict__ b,
                          float* __restrict__ y) {
    int l = blockIdx.x * blockDim.x + threadIdx.x;
    if (l >= LL) return;
    const float* a = acc + l * DINc;
    float m = 0.f;
    for (int c = 0; c < DINc; ++c) m += a[c];
    m *= (1.f / DINc);
    float v = 0.f;
    for (int c = 0; c < DINc; ++c) { float d = a[c] - m; v += d * d; }
    v *= (1.f / DINc);
    float r = rsqrtf(v + 1e-5f);
    for (int c = 0; c < DINc; ++c) {
        float zz = z_cm[(long)c * LL + l];
        y[l * DINc + c] = ((a[c] - m) * r * w[c] + b[c]) * silu_(zz);
    }
}

// ---------------- K10: out_proj + skip1 ----------------
__global__ void k_outproj(const float* __restrict__ y, const float* __restrict__ opw,
                          const float* __restrict__ inp, const float* __restrict__ skip1,
                          float* __restrict__ xafter) {
    int idx = blockIdx.x * blockDim.x + threadIdx.x;
    if (idx >= LL * CC) return;
    int c = idx % CC;
    int l = idx / CC;
    const float* yr = y + l * DINc;
    const float* wr = opw + c * DINc;
    float s = 0.f;
    for (int e = 0; e < DINc; ++e) s += yr[e] * wr[e];
    xafter[l * CC + c] = inp[l * CC + c] * skip1[c] + s;
}

// ---------------- K11: LN2 -> channel-major ----------------
__global__ void k_ln2(const float* __restrict__ xafter, const float* __restrict__ w,
                      const float* __restrict__ b, float* __restrict__ y2) {
    int l = blockIdx.x * blockDim.x + threadIdx.x;
    if (l >= LL) return;
    const float* p = xafter + l * CC;
    float m = 0.f;
    for (int c = 0; c < CC; ++c) m += p[c];
    m *= (1.f / CC);
    float v = 0.f;
    for (int c = 0; c < CC; ++c) { float d = p[c] - m; v += d * d; }
    v *= (1.f / CC);
    float r = rsqrtf(v + 1e-5f);
    for (int c = 0; c < CC; ++c) y2[c * LL + l] = (p[c] - m) * r * w[c] + b[c];
}

// ---------------- K12: conv3d 96->32, 8-way ic-split, 4 ocg ----------------
// grid: 32 g x 32 l-blocks; g: ocg = g&3, isp = g>>2 (12 ic each)
__global__ void k_conv1(const float* __restrict__ y2, const float* __restrict__ wT,
                        float* __restrict__ part) {
    int bx = blockIdx.x;
    int g = bx >> 5;
    int l = ((bx & 31) << 8) + threadIdx.x;
    int ocg = g & 3;
    int isp = g >> 2;
    int w = l & (Ww - 1);
    int h = (l >> 5) & (Hh - 1);
    int d = l >> 9;
    float a[8];
    #pragma unroll
    for (int j = 0; j < 8; ++j) a[j] = 0.f;
    for (int ic = isp * 12; ic < isp * 12 + 12; ++ic) {
        const float* xp = y2 + (long)ic * LL;
        const float* wb = wT + ic * 27 * 32 + ocg * 8;
        for (int kd = -1; kd <= 1; ++kd) {
            int dd = d + kd; if ((unsigned)dd >= Dd) continue;
            for (int kh = -1; kh <= 1; ++kh) {
                int hh = h + kh; if ((unsigned)hh >= Hh) continue;
                int rowb = (dd * Hh + hh) * Ww;
                int tapb = ((kd + 1) * 9 + (kh + 1) * 3) * 32;
                #pragma unroll
                for (int kw = -1; kw <= 1; ++kw) {
                    int ww2 = w + kw; if ((unsigned)ww2 >= Ww) continue;
                    float x = xp[rowb + ww2];
                    const float4* wv = (const float4*)(wb + tapb + (kw + 1) * 32);
                    float4 wa = wv[0], wbv = wv[1];
                    a[0] += x * wa.x;  a[1] += x * wa.y;  a[2] += x * wa.z;  a[3] += x * wa.w;
                    a[4] += x * wbv.x; a[5] += x * wbv.y; a[6] += x * wbv.z; a[7] += x * wbv.w;
                }
            }
        }
    }
    float* pp = part + ((long)(isp * 32 + ocg * 8)) * LL + l;
    #pragma unroll
    for (int j = 0; j < 8; ++j) pp[(long)j * LL] = a[j];
}

// ---------------- K12b: t1 = GELU(sum 8 partials + bias) ----------------
__global__ void k_gelusum(const float* __restrict__ part, const float* __restrict__ b1,
                          float* __restrict__ t1) {
    int idx = blockIdx.x * blockDim.x + threadIdx.x;
    if (idx >= 32 * LL) return;
    int l = idx & (LL - 1);
    int oc = idx >> 13;
    float s = b1[oc];
    #pragma unroll
    for (int isp = 0; isp < 8; ++isp)
        s += part[((long)(isp * 32 + oc)) * LL + l];
    t1[oc * LL + l] = 0.5f * s * (1.f + erff(s * 0.70710678118654752f));
}

// ---------------- K13: conv3d 32->96, 4-way ic-split, 12 ocg ----------------
// grid: 48 g x 32 l-blocks; g: ocg = g%12, isp = g/12 (8 ic each)
__global__ void k_conv2(const float* __restrict__ t1, const float* __restrict__ wT,
                        float* __restrict__ part) {
    int bx = blockIdx.x;
    int g = bx >> 5;
    int l = ((bx & 31) << 8) + threadIdx.x;
    int ocg = g % 12;
    int isp = g / 12;
    int w = l & (Ww - 1);
    int h = (l >> 5) & (Hh - 1);
    int d = l >> 9;
    float a[8];
    #pragma unroll
    for (int j = 0; j < 8; ++j) a[j] = 0.f;
    for (int ic = isp * 8; ic < isp * 8 + 8; ++ic) {
        const float* xp = t1 + (long)ic * LL;
        const float* wb = wT + ic * 27 * 96 + ocg * 8;
        for (int kd = -1; kd <= 1; ++kd) {
            int dd = d + kd; if ((unsigned)dd >= Dd) continue;
            for (int kh = -1; kh <= 1; ++kh) {
                int hh = h + kh; if ((unsigned)hh >= Hh) continue;
                int rowb = (dd * Hh + hh) * Ww;
                int tapb = ((kd + 1) * 9 + (kh + 1) * 3) * 96;
                #pragma unroll
                for (int kw = -1; kw <= 1; ++kw) {
                    int ww2 = w + kw; if ((unsigned)ww2 >= Ww) continue;
                    float x = xp[rowb + ww2];
                    const float4* wv = (const float4*)(wb + tapb + (kw + 1) * 96);
                    float4 wa = wv[0], wbv = wv[1];
                    a[0] += x * wa.x;  a[1] += x * wa.y;  a[2] += x * wa.z;  a[3] += x * wa.w;
                    a[4] += x * wbv.x; a[5] += x * wbv.y; a[6] += x * wbv.z; a[7] += x * wbv.w;
                }
            }
        }
    }
    float* pp = part + ((long)(isp * 96 + ocg * 8)) * LL + l;
    #pragma unroll
    for (int j = 0; j < 8; ++j) pp[(long)j * LL] = a[j];
}

// ---------------- K13b: t2 = sum 4 partials + bias ----------------
__global__ void k_conv2sum(const float* __restrict__ part, const float* __restrict__ b2,
                           float* __restrict__ t2) {
    int idx = blockIdx.x * blockDim.x + threadIdx.x;
    if (idx >= 96 * LL) return;
    int l = idx & (LL - 1);
    int oc = idx >> 13;
    float s = b2[oc];
    #pragma unroll
    for (int isp = 0; isp < 4; ++isp)
        s += part[((long)(isp * 96 + oc)) * LL + l];
    t2[oc * LL + l] = s;
}

// ---------------- K14a: per-channel mean ----------------
__global__ void k_mean(const float* __restrict__ t2, float* __restrict__ mbuf) {
    __shared__ float sm[256];
    int c = blockIdx.x;
    float a = 0.f;
    for (int l = threadIdx.x; l < LL; l += 256) a += t2[c * LL + l];
    sm[threadIdx.x] = a;
    __syncthreads();
    for (int o = 128; o > 0; o >>= 1) {
        if (threadIdx.x < o) sm[threadIdx.x] += sm[threadIdx.x + o];
        __syncthreads();
    }
    if (threadIdx.x == 0) mbuf[c] = sm[0] * (1.f / LL);
}

// ---------------- K14b: channel-attention MLP ----------------
__global__ void k_mlp(const float* __restrict__ mbuf, const float* __restrict__ w1,
                      const float* __restrict__ b1, const float* __restrict__ w2,
                      const float* __restrict__ b2, float* __restrict__ v2) {
    __shared__ float v[48];
    int t = threadIdx.x;
    if (t < 48) {
        float s = b1[t];
        for (int c = 0; c < 96; ++c) s += mbuf[c] * w1[t * 96 + c];
        v[t] = fmaxf(s, 0.f);
    }
    __syncthreads();
    if (t < 96) {
        float s = b2[t];
        for (int j = 0; j < 48; ++j) s += v[j] * w2[t * 48 + j];
        v2[t] = 1.f / (1.f + __expf(-s));
    }
}

// ---------------- K15: final residual ----------------
__global__ void k_final(const float* __restrict__ xafter, const float* __restrict__ skip2,
                        const float* __restrict__ t2, const float* __restrict__ v2,
                        float* __restrict__ out) {
    int idx = blockIdx.x * blockDim.x + threadIdx.x;
    if (idx >= LL * CC) return;
    int c = idx % CC;
    int l = idx / CC;
    out[l * CC + c] = xafter[l * CC + c] * skip2[c] + t2[c * LL + l] * v2[c];
}

// ---------------- workspace layout (float offsets) ----------------
static const size_t OFF_XS     = 0;          // 8*96*8192 (xs -> ys; conv partials after combine)
static const size_t OFF_Z      = 6291456;    // 786432 (z channel-major)
static const size_t OFF_XCM    = 7077888;    // 786432 (pre-conv x; reused as acc)
static const size_t OFF_XN     = 7864320;    // 786432 (xn_cm; reused as y)
static const size_t OFF_DTRAW  = 8650752;    // 393216
static const size_t OFF_BB     = 9043968;    // 1048576
static const size_t OFF_CB     = 10092544;   // 1048576
static const size_t OFF_XAFTER = 11141120;   // 786432 (scan: Ap reuses this)
static const size_t OFF_Y2     = 11927552;   // 786432 (scan: Bc reuses this)
static const size_t OFF_T1     = 12713984;   // 262144
static const size_t OFF_T2     = 12976128;   // 786432 (scan: hs reuses this)
static const size_t OFF_MV     = 13762560;   // 256
static const size_t OFF_WT1    = 13762816;   // 82944
static const size_t OFF_WT2    = 13845760;   // 82944
static const size_t OFF_IPT    = 13928704;   // 18432
static const size_t OFF_XPT    = 13947136;   // 29184  (end ~13976320 fl = 55.9 MB)

extern "C" void kernel_launch(void* const* d_in, const int* in_sizes, int n_in,
                              void* d_out, int out_size, void* d_ws, size_t ws_size,
                              hipStream_t stream) {
    const float* inp    = (const float*)d_in[0];
    const float* ln1_w  = (const float*)d_in[2];
    const float* ln1_b  = (const float*)d_in[3];
    const float* skip1  = (const float*)d_in[4];
    const float* skip2  = (const float*)d_in[5];
    const float* ln2_w  = (const float*)d_in[6];
    const float* ln2_b  = (const float*)d_in[7];
    const float* inpj   = (const float*)d_in[8];
    const float* conv_w = (const float*)d_in[9];
    const float* conv_b = (const float*)d_in[10];
    const float* xpw    = (const float*)d_in[11];
    const float* dt_w   = (const float*)d_in[12];
    const float* dt_b   = (const float*)d_in[13];
    const float* A_logs = (const float*)d_in[14];
    const float* Ds     = (const float*)d_in[15];
    const float* onw    = (const float*)d_in[16];
    const float* onb    = (const float*)d_in[17];
    const float* opw    = (const float*)d_in[18];
    const float* cab_w1 = (const float*)d_in[19];
    const float* cab_b1 = (const float*)d_in[20];
    const float* cab_w2 = (const float*)d_in[21];
    const float* cab_b2 = (const float*)d_in[22];
    const float* ca_w1  = (const float*)d_in[23];
    const float* ca_b1  = (const float*)d_in[24];
    const float* ca_w2  = (const float*)d_in[25];
    const float* ca_b2  = (const float*)d_in[26];

    float* ws = (float*)d_ws;
    float* xs     = ws + OFF_XS;
    float* zbuf   = ws + OFF_Z;
    float* xcm    = ws + OFF_XCM;
    float* xn     = ws + OFF_XN;
    float* dtraw  = ws + OFF_DTRAW;
    float* Bb     = ws + OFF_BB;
    float* Cb     = ws + OFF_CB;
    float* xafter = ws + OFF_XAFTER;
    float* y2     = ws + OFF_Y2;
    float* t1     = ws + OFF_T1;
    float* t2     = ws + OFF_T2;
    float* mv     = ws + OFF_MV;
    float* wT1    = ws + OFF_WT1;
    float* wT2    = ws + OFF_WT2;
    float* ipT    = ws + OFF_IPT;
    float* xpT    = ws + OFF_XPT;
    float* acc    = xcm;                 // reuse (xcm dead after dwconv)
    float* ybuf   = xn;                  // reuse (xn dead after inproj)
    float* Ap     = xafter;              // reuse (xafter written at k_outproj)
    float* Bc     = y2;                  // reuse (y2 written at k_ln2)
    float* hst    = t2;                  // reuse (t2 written at k_conv2sum)
    float* part1  = xs;                  // 8*32*8192 = 2097152 (xs dead after combine)
    float* part2  = xs + 2097152;        // 4*96*8192 = 3145728

    float* out = (float*)d_out;
    #define GRID(n) dim3((unsigned)(((n) + 255) / 256)), dim3(256)

    hipLaunchKernelGGL(k_ln1,     GRID(LL),                   0, stream, inp, ln1_w, ln1_b, xn);
    hipLaunchKernelGGL(k_wtrans,  GRID(82944),                0, stream, inpj, xpw, cab_w1, cab_w2, ipT, xpT, wT1, wT2);
    hipLaunchKernelGGL(k_inproj,  dim3(768), dim3(256),       0, stream, xn, ipT, xcm, zbuf);
    hipLaunchKernelGGL(k_dwconv,  GRID(DINc * LL),            0, stream, xcm, conv_w, conv_b, xs);
    hipLaunchKernelGGL(k_perm,    GRID(7 * DINc * LL),        0, stream, xs);
    hipLaunchKernelGGL(k_xdbl,    dim3(256), dim3(256),       0, stream, xs, xpT, dtraw, Bb, Cb);
    hipLaunchKernelGGL(k_scan1,   GRID(KK * DINc * NCH * NN), 0, stream, xs, dtraw, Bb, A_logs, dt_w, dt_b, Ap, Bc);
    hipLaunchKernelGGL(k_scan2,   GRID(KK * DINc * NN),       0, stream, Ap, Bc, hst);
    hipLaunchKernelGGL(k_scan3,   GRID(KK * DINc * NCH * NN), 0, stream, xs, dtraw, Bb, Cb, A_logs, dt_w, dt_b, Ds, hst);
    hipLaunchKernelGGL(k_combine, GRID(LL * DINc),            0, stream, xs, acc);
    hipLaunchKernelGGL(k_outnorm, GRID(LL),                   0, stream, acc, zbuf, onw, onb, ybuf);
    hipLaunchKernelGGL(k_outproj, GRID(LL * CC),              0, stream, ybuf, opw, inp, skip1, xafter);
    hipLaunchKernelGGL(k_ln2,     GRID(LL),                   0, stream, xafter, ln2_w, ln2_b, y2);
    hipLaunchKernelGGL(k_conv1,   dim3(1024), dim3(256),      0, stream, y2, wT1, part1);
    hipLaunchKernelGGL(k_gelusum, GRID(32 * LL),              0, stream, part1, cab_b1, t1);
    hipLaunchKernelGGL(k_conv2,   dim3(1536), dim3(256),      0, stream, t1, wT2, part2);
    hipLaunchKernelGGL(k_conv2sum,GRID(96 * LL),              0, stream, part2, cab_b2, t2);
    hipLaunchKernelGGL(k_mean,    dim3(96), dim3(256),        0, stream, t2, mv);
    hipLaunchKernelGGL(k_mlp,     dim3(1), dim3(128),         0, stream, mv, ca_w1, ca_b1, ca_w2, ca_b2, mv + 96);
    hipLaunchKernelGGL(k_final,   GRID(LL * CC),              0, stream, xafter, skip2, t2, mv + 96, out);
    #undef GRID
}

// Round 6
// 461.324 us; speedup vs baseline: 14.6274x; 1.1420x over previous
//
#include <hip/hip_runtime.h>
#include <math.h>

#define LL 8192
#define CC 96
#define DINc 96
#define NN 16
#define RR 6
#define KK 8
#define Dd 16
#define Hh 16
#define Ww 32
#define NCH 32
#define CHL 256   // LL / NCH

__constant__ int Pc_[4][3] = {{0,1,2},{1,2,0},{2,0,1},{2,1,0}};

__device__ __forceinline__ float silu_(float x){ return x / (1.f + __expf(-x)); }

// ---------------- K1: LN over C at each l -> xn CHANNEL-MAJOR [c][l] ----------------
__global__ void k_ln1(const float* __restrict__ inp, const float* __restrict__ w,
                      const float* __restrict__ b, float* __restrict__ xn_cm) {
    int l = blockIdx.x * blockDim.x + threadIdx.x;
    if (l >= LL) return;
    const float* p = inp + l * CC;
    float m = 0.f;
    for (int c = 0; c < CC; ++c) m += p[c];
    m *= (1.f / CC);
    float v = 0.f;
    for (int c = 0; c < CC; ++c) { float d = p[c] - m; v += d * d; }
    v *= (1.f / CC);
    float r = rsqrtf(v + 1e-6f);
    for (int c = 0; c < CC; ++c) xn_cm[c * LL + l] = (p[c] - m) * r * w[c] + b[c];
}

// ---------------- KW: transpose weights (in_proj, x_proj, cab convs) ----------------
__global__ void k_wtrans(const float* __restrict__ inpj, const float* __restrict__ xpw,
                         const float* __restrict__ w1, const float* __restrict__ w2,
                         float* __restrict__ ipT, float* __restrict__ xpT,
                         float* __restrict__ wT1, float* __restrict__ wT2) {
    int idx = blockIdx.x * blockDim.x + threadIdx.x;
    if (idx < 82944) {   // wT1: [ic][tap][oc=32]
        int oc = idx & 31; int tap = (idx >> 5) % 27; int ic = idx / (32 * 27);
        wT1[idx] = w1[(oc * 96 + ic) * 27 + tap];
    }
    if (idx < 82944) {   // wT2: [ic][tap][oc=96]
        int oc = idx % 96; int tap = (idx / 96) % 27; int ic = idx / (96 * 27);
        wT2[idx] = w2[(oc * 32 + ic) * 27 + tap];
    }
    if (idx < 18432) {   // ipT: [c][e=192]
        int e = idx % 192; int c = idx / 192;
        ipT[idx] = inpj[e * 96 + c];
    }
    if (idx < 29184) {   // xpT: [k][c][e=38]
        int e = idx % 38; int c = (idx / 38) % 96; int k = idx / (38 * 96);
        xpT[idx] = xpw[(k * 38 + e) * 96 + c];
    }
}

// ---------------- K2: in_proj, 8-e register block, uniform weights ----------------
__global__ void k_inproj(const float* __restrict__ xn_cm, const float* __restrict__ ipT,
                         float* __restrict__ xcm, float* __restrict__ z_cm) {
    int bx = blockIdx.x;
    int eb = bx >> 5;                       // 0..23 (uniform)
    int l  = ((bx & 31) << 8) + threadIdx.x;
    int e0 = eb << 3;
    float a[8];
    #pragma unroll
    for (int j = 0; j < 8; ++j) a[j] = 0.f;
    const float* wp = ipT + e0;
    for (int c = 0; c < CC; ++c) {
        float x = xn_cm[c * LL + l];
        const float4* wv = (const float4*)(wp + c * 192);
        float4 wa = wv[0], wb = wv[1];
        a[0] += x * wa.x; a[1] += x * wa.y; a[2] += x * wa.z; a[3] += x * wa.w;
        a[4] += x * wb.x; a[5] += x * wb.y; a[6] += x * wb.z; a[7] += x * wb.w;
    }
    float* dst = (e0 < DINc) ? (xcm + (long)e0 * LL) : (z_cm + (long)(e0 - DINc) * LL);
    #pragma unroll
    for (int j = 0; j < 8; ++j) dst[(long)j * LL + l] = a[j];
}

// ---------------- K3: depthwise conv3d + SiLU -> xs[0] ----------------
__global__ void k_dwconv(const float* __restrict__ xcm, const float* __restrict__ cw,
                         const float* __restrict__ cb, float* __restrict__ xs0) {
    int idx = blockIdx.x * blockDim.x + threadIdx.x;
    if (idx >= DINc * LL) return;
    int l = idx & (LL - 1);
    int c = idx >> 13;
    int w = l & (Ww - 1);
    int h = (l >> 5) & (Hh - 1);
    int d = l >> 9;
    float s = cb[c];
    const float* xp = xcm + c * LL;
    const float* wp = cw + c * 27;
    for (int kd = -1; kd <= 1; ++kd) {
        int dd = d + kd; if ((unsigned)dd >= Dd) continue;
        for (int kh = -1; kh <= 1; ++kh) {
            int hh = h + kh; if ((unsigned)hh >= Hh) continue;
            for (int kw = -1; kw <= 1; ++kw) {
                int ww2 = w + kw; if ((unsigned)ww2 >= Ww) continue;
                s += xp[(dd * Hh + hh) * Ww + ww2] * wp[(kd + 1) * 9 + (kh + 1) * 3 + (kw + 1)];
            }
        }
    }
    xs0[c * LL + l] = silu_(s);
}

// ---------------- K4: build xs[1..7] ----------------
__global__ void k_perm(float* __restrict__ xs) {
    int idx = blockIdx.x * blockDim.x + threadIdx.x;
    if (idx >= 7 * DINc * LL) return;
    int l = idx & (LL - 1);
    int c = (idx >> 13) % DINc;
    int k = idx / (DINc * LL) + 1;
    int i  = (k < 4) ? k : (k - 4);
    int lp = (k < 4) ? l : (LL - 1 - l);
    int p0 = Pc_[i][0], p1 = Pc_[i][1], p2 = Pc_[i][2];
    const int sp[3] = {Dd, Hh, Ww};
    int pd1 = sp[p1], pd2 = sp[p2];
    int i2 = lp % pd2;
    int t  = lp / pd2;
    int i1 = t % pd1;
    int i0 = t / pd1;
    int coord[3];
    coord[p0] = i0; coord[p1] = i1; coord[p2] = i2;
    int o = (coord[0] * Hh + coord[1]) * Ww + coord[2];
    xs[(k * DINc + c) * LL + l] = xs[c * LL + o];
}

// ---------------- K5: x_dbl, 38 accumulators per (k,l), xs read once ----------------
__global__ void k_xdbl(const float* __restrict__ xs, const float* __restrict__ xpT,
                       float* __restrict__ dtraw, float* __restrict__ Bb, float* __restrict__ Cb) {
    int bx = blockIdx.x;
    int k = bx >> 5;                        // uniform
    int l = ((bx & 31) << 8) + threadIdx.x;
    float acc[38];
    #pragma unroll
    for (int e = 0; e < 38; ++e) acc[e] = 0.f;
    const float* xb = xs + (long)k * DINc * LL + l;
    const float* wb = xpT + k * DINc * 38;
    for (int c = 0; c < DINc; ++c) {
        float x = xb[(long)c * LL];
        const float* wr = wb + c * 38;
        #pragma unroll
        for (int e = 0; e < 38; ++e) acc[e] += x * wr[e];
    }
    #pragma unroll
    for (int r = 0; r < RR; ++r) dtraw[(k * RR + r) * LL + l] = acc[r];
    float* Bp = Bb + ((long)k * LL + l) * NN;
    float* Cp = Cb + ((long)k * LL + l) * NN;
    #pragma unroll
    for (int n = 0; n < NN; ++n) { Bp[n] = acc[RR + n]; Cp[n] = acc[RR + NN + n]; }
}

// ---------------- softplus ----------------
__device__ __forceinline__ float softplus_(float x) {
    return (x > 20.f) ? x : __logf(1.f + __expf(x));
}

// ---------------- K7a: chunk-local scan -> (Aprod, Bacc); LDS (dt,du) pair broadcast ----------------
__global__ void k_scan1(const float* __restrict__ xs, const float* __restrict__ dtraw,
                        const float* __restrict__ Bb, const float* __restrict__ A_logs,
                        const float* __restrict__ dt_w, const float* __restrict__ dt_b,
                        float* __restrict__ Ap, float* __restrict__ Bc) {
    __shared__ float2 sdu[256];
    int t = blockIdx.x * blockDim.x + threadIdx.x;
    int n = t & 15;
    int gc = t >> 4;
    if (gc >= KK * DINc * NCH) return;
    int gbase = threadIdx.x & ~15;
    int grp = gc >> 5;
    int chunk = gc & (NCH - 1);
    int k = grp / DINc;
    float A_n = -__expf(A_logs[grp * NN + n]);
    float w0 = dt_w[grp * RR + 0], w1 = dt_w[grp * RR + 1], w2 = dt_w[grp * RR + 2];
    float w3 = dt_w[grp * RR + 3], w4 = dt_w[grp * RR + 4], w5 = dt_w[grp * RR + 5];
    float dtb = dt_b[grp];
    const float* drb  = dtraw + (long)k * RR * LL + chunk * CHL;
    const float* urow = xs + (long)grp * LL + chunk * CHL;
    const float* Bblk = Bb + ((long)k * LL + chunk * CHL) * NN + n;
    float hc = 0.f, dsuml = 0.f;
    for (int base = 0; base < CHL; base += 16) {
        int lm = base + n;
        float dtl = dtb + drb[lm] * w0 + drb[LL + lm] * w1 + drb[2 * LL + lm] * w2
                        + drb[3 * LL + lm] * w3 + drb[4 * LL + lm] * w4 + drb[5 * LL + lm] * w5;
        float dt_lane = softplus_(dtl);
        float u_lane  = urow[lm];
        sdu[threadIdx.x] = make_float2(dt_lane, dt_lane * u_lane);
        dsuml += dt_lane;
        #pragma unroll
        for (int j = 0; j < 16; ++j) {
            float2 v = sdu[gbase + j];
            float a  = __expf(v.x * A_n);
            hc = a * hc + v.y * Bblk[(base + j) * NN];
        }
    }
    dsuml += __shfl_xor(dsuml, 1, 16);
    dsuml += __shfl_xor(dsuml, 2, 16);
    dsuml += __shfl_xor(dsuml, 4, 16);
    dsuml += __shfl_xor(dsuml, 8, 16);
    int o = (grp * NN + n) * NCH + chunk;
    Ap[o] = __expf(A_n * dsuml);
    Bc[o] = hc;
}

// ---------------- K7b: combine chunk transfers ----------------
__global__ void k_scan2(const float* __restrict__ Ap, const float* __restrict__ Bc,
                        float* __restrict__ hs) {
    int t = blockIdx.x * blockDim.x + threadIdx.x;
    if (t >= KK * DINc * NN) return;
    int base = t * NCH;
    float h = 0.f;
    for (int c = 0; c < NCH; ++c) {
        hs[base + c] = h;
        h = Ap[base + c] * h + Bc[base + c];
    }
}

// ---------------- K7c: final scan; LDS pair broadcast + deferred 4-stage tree reduce ----------------
__global__ void k_scan3(float* __restrict__ xs_ys, const float* __restrict__ dtraw,
                        const float* __restrict__ Bb, const float* __restrict__ Cb,
                        const float* __restrict__ A_logs, const float* __restrict__ dt_w,
                        const float* __restrict__ dt_b, const float* __restrict__ Ds,
                        const float* __restrict__ hs) {
    __shared__ float2 sdu[256];
    int t = blockIdx.x * blockDim.x + threadIdx.x;
    int n = t & 15;
    int gc = t >> 4;
    if (gc >= KK * DINc * NCH) return;
    int gbase = threadIdx.x & ~15;
    int grp = gc >> 5;
    int chunk = gc & (NCH - 1);
    int k = grp / DINc;
    float A_n = -__expf(A_logs[grp * NN + n]);
    float w0 = dt_w[grp * RR + 0], w1 = dt_w[grp * RR + 1], w2 = dt_w[grp * RR + 2];
    float w3 = dt_w[grp * RR + 3], w4 = dt_w[grp * RR + 4], w5 = dt_w[grp * RR + 5];
    float dtb = dt_b[grp];
    float Dv  = Ds[grp];
    const float* drb  = dtraw + (long)k * RR * LL + chunk * CHL;
    const float* Bblk = Bb + ((long)k * LL + chunk * CHL) * NN + n;
    const float* Cblk = Cb + ((long)k * LL + chunk * CHL) * NN + n;
    float* urow = xs_ys + (long)grp * LL + chunk * CHL;
    float hc = hs[(grp * NN + n) * NCH + chunk];
    bool b0 = (n & 1), b1 = ((n >> 1) & 1), b2 = ((n >> 2) & 1), b3 = (n >> 3);
    for (int base = 0; base < CHL; base += 16) {
        int lm = base + n;
        float dtl = dtb + drb[lm] * w0 + drb[LL + lm] * w1 + drb[2 * LL + lm] * w2
                        + drb[3 * LL + lm] * w3 + drb[4 * LL + lm] * w4 + drb[5 * LL + lm] * w5;
        float dt_lane = softplus_(dtl);
        float u_lane  = urow[lm];
        sdu[threadIdx.x] = make_float2(dt_lane, dt_lane * u_lane);
        float p[16];
        #pragma unroll
        for (int j = 0; j < 16; ++j) {
            float2 v = sdu[gbase + j];
            float a  = __expf(v.x * A_n);
            hc = a * hc + v.y * Bblk[(base + j) * NN];
            p[j] = hc * Cblk[(base + j) * NN];
        }
        // 4-stage recursive halving: lane n ends with sum over lanes of p[n]
        float q[8];
        #pragma unroll
        for (int m = 0; m < 8; ++m) {
            float s = b0 ? p[2*m] : p[2*m+1];
            float r = __shfl_xor(s, 1, 16);
            q[m] = (b0 ? p[2*m+1] : p[2*m]) + r;
        }
        float r4[4];
        #pragma unroll
        for (int m = 0; m < 4; ++m) {
            float s = b1 ? q[2*m] : q[2*m+1];
            float r = __shfl_xor(s, 2, 16);
            r4[m] = (b1 ? q[2*m+1] : q[2*m]) + r;
        }
        float t2r[2];
        #pragma unroll
        for (int m = 0; m < 2; ++m) {
            float s = b2 ? r4[2*m] : r4[2*m+1];
            float r = __shfl_xor(s, 4, 16);
            t2r[m] = (b2 ? r4[2*m+1] : r4[2*m]) + r;
        }
        float s = b3 ? t2r[0] : t2r[1];
        float r = __shfl_xor(s, 8, 16);
        float yv = (b3 ? t2r[1] : t2r[0]) + r;
        urow[base + n] = yv + Dv * u_lane;
    }
}

// ---------------- K8: inverse-permute + sum 8 directions ----------------
__global__ void k_combine(const float* __restrict__ ys, float* __restrict__ acc) {
    int idx = blockIdx.x * blockDim.x + threadIdx.x;
    if (idx >= LL * DINc) return;
    int c = idx % DINc;
    int l = idx / DINc;
    int w = l & (Ww - 1);
    int h = (l >> 5) & (Hh - 1);
    int d = l >> 9;
    int coord[3] = {d, h, w};
    const int sp[3] = {Dd, Hh, Ww};
    float s = 0.f;
    #pragma unroll
    for (int i = 0; i < 4; ++i) {
        int p0 = Pc_[i][0], p1 = Pc_[i][1], p2 = Pc_[i][2];
        int lp = (coord[p0] * sp[p1] + coord[p1]) * sp[p2] + coord[p2];
        s += ys[(long)(i * DINc + c) * LL + lp];
        s += ys[(long)((4 + i) * DINc + c) * LL + (LL - 1 - lp)];
    }
    acc[l * DINc + c] = s;
}

// ---------------- K9: out_norm LN * silu(z_cm) ----------------
__global__ void k_outnorm(const float* __restrict__ acc, const float* __restrict__ z_cm,
                          const float* __restrict__ w, const float* __restrict__ b,
                          float* __restrict__ y) {
    int l = blockIdx.x * blockDim.x + threadIdx.x;
    if (l >= LL) return;
    const float* a = acc + l * DINc;
    float m = 0.f;
    for (int c = 0; c < DINc; ++c) m += a[c];
    m *= (1.f / DINc);
    float v = 0.f;
    for (int c = 0; c < DINc; ++c) { float d = a[c] - m; v += d * d; }
    v *= (1.f / DINc);
    float r = rsqrtf(v + 1e-5f);
    for (int c = 0; c < DINc; ++c) {
        float zz = z_cm[(long)c * LL + l];
        y[l * DINc + c] = ((a[c] - m) * r * w[c] + b[c]) * silu_(zz);
    }
}

// ---------------- K10: out_proj + skip1 ----------------
__global__ void k_outproj(const float* __restrict__ y, const float* __restrict__ opw,
                          const float* __restrict__ inp, const float* __restrict__ skip1,
                          float* __restrict__ xafter) {
    int idx = blockIdx.x * blockDim.x + threadIdx.x;
    if (idx >= LL * CC) return;
    int c = idx % CC;
    int l = idx / CC;
    const float* yr = y + l * DINc;
    const float* wr = opw + c * DINc;
    float s = 0.f;
    for (int e = 0; e < DINc; ++e) s += yr[e] * wr[e];
    xafter[l * CC + c] = inp[l * CC + c] * skip1[c] + s;
}

// ---------------- K11: LN2 -> channel-major ----------------
__global__ void k_ln2(const float* __restrict__ xafter, const float* __restrict__ w,
                      const float* __restrict__ b, float* __restrict__ y2) {
    int l = blockIdx.x * blockDim.x + threadIdx.x;
    if (l >= LL) return;
    const float* p = xafter + l * CC;
    float m = 0.f;
    for (int c = 0; c < CC; ++c) m += p[c];
    m *= (1.f / CC);
    float v = 0.f;
    for (int c = 0; c < CC; ++c) { float d = p[c] - m; v += d * d; }
    v *= (1.f / CC);
    float r = rsqrtf(v + 1e-5f);
    for (int c = 0; c < CC; ++c) y2[c * LL + l] = (p[c] - m) * r * w[c] + b[c];
}

// ---------------- K12: conv3d 96->32, 8-way ic-split, 4 ocg ----------------
__global__ void k_conv1(const float* __restrict__ y2, const float* __restrict__ wT,
                        float* __restrict__ part) {
    int bx = blockIdx.x;
    int g = bx >> 5;
    int l = ((bx & 31) << 8) + threadIdx.x;
    int ocg = g & 3;
    int isp = g >> 2;
    int w = l & (Ww - 1);
    int h = (l >> 5) & (Hh - 1);
    int d = l >> 9;
    float a[8];
    #pragma unroll
    for (int j = 0; j < 8; ++j) a[j] = 0.f;
    for (int ic = isp * 12; ic < isp * 12 + 12; ++ic) {
        const float* xp = y2 + (long)ic * LL;
        const float* wb = wT + ic * 27 * 32 + ocg * 8;
        for (int kd = -1; kd <= 1; ++kd) {
            int dd = d + kd; if ((unsigned)dd >= Dd) continue;
            for (int kh = -1; kh <= 1; ++kh) {
                int hh = h + kh; if ((unsigned)hh >= Hh) continue;
                int rowb = (dd * Hh + hh) * Ww;
                int tapb = ((kd + 1) * 9 + (kh + 1) * 3) * 32;
                #pragma unroll
                for (int kw = -1; kw <= 1; ++kw) {
                    int ww2 = w + kw; if ((unsigned)ww2 >= Ww) continue;
                    float x = xp[rowb + ww2];
                    const float4* wv = (const float4*)(wb + tapb + (kw + 1) * 32);
                    float4 wa = wv[0], wbv = wv[1];
                    a[0] += x * wa.x;  a[1] += x * wa.y;  a[2] += x * wa.z;  a[3] += x * wa.w;
                    a[4] += x * wbv.x; a[5] += x * wbv.y; a[6] += x * wbv.z; a[7] += x * wbv.w;
                }
            }
        }
    }
    float* pp = part + ((long)(isp * 32 + ocg * 8)) * LL + l;
    #pragma unroll
    for (int j = 0; j < 8; ++j) pp[(long)j * LL] = a[j];
}

// ---------------- K12b: t1 = GELU(sum 8 partials + bias) ----------------
__global__ void k_gelusum(const float* __restrict__ part, const float* __restrict__ b1,
                          float* __restrict__ t1) {
    int idx = blockIdx.x * blockDim.x + threadIdx.x;
    if (idx >= 32 * LL) return;
    int l = idx & (LL - 1);
    int oc = idx >> 13;
    float s = b1[oc];
    #pragma unroll
    for (int isp = 0; isp < 8; ++isp)
        s += part[((long)(isp * 32 + oc)) * LL + l];
    t1[oc * LL + l] = 0.5f * s * (1.f + erff(s * 0.70710678118654752f));
}

// ---------------- K13: conv3d 32->96, 4-way ic-split, 12 ocg ----------------
__global__ void k_conv2(const float* __restrict__ t1, const float* __restrict__ wT,
                        float* __restrict__ part) {
    int bx = blockIdx.x;
    int g = bx >> 5;
    int l = ((bx & 31) << 8) + threadIdx.x;
    int ocg = g % 12;
    int isp = g / 12;
    int w = l & (Ww - 1);
    int h = (l >> 5) & (Hh - 1);
    int d = l >> 9;
    float a[8];
    #pragma unroll
    for (int j = 0; j < 8; ++j) a[j] = 0.f;
    for (int ic = isp * 8; ic < isp * 8 + 8; ++ic) {
        const float* xp = t1 + (long)ic * LL;
        const float* wb = wT + ic * 27 * 96 + ocg * 8;
        for (int kd = -1; kd <= 1; ++kd) {
            int dd = d + kd; if ((unsigned)dd >= Dd) continue;
            for (int kh = -1; kh <= 1; ++kh) {
                int hh = h + kh; if ((unsigned)hh >= Hh) continue;
                int rowb = (dd * Hh + hh) * Ww;
                int tapb = ((kd + 1) * 9 + (kh + 1) * 3) * 96;
                #pragma unroll
                for (int kw = -1; kw <= 1; ++kw) {
                    int ww2 = w + kw; if ((unsigned)ww2 >= Ww) continue;
                    float x = xp[rowb + ww2];
                    const float4* wv = (const float4*)(wb + tapb + (kw + 1) * 96);
                    float4 wa = wv[0], wbv = wv[1];
                    a[0] += x * wa.x;  a[1] += x * wa.y;  a[2] += x * wa.z;  a[3] += x * wa.w;
                    a[4] += x * wbv.x; a[5] += x * wbv.y; a[6] += x * wbv.z; a[7] += x * wbv.w;
                }
            }
        }
    }
    float* pp = part + ((long)(isp * 96 + ocg * 8)) * LL + l;
    #pragma unroll
    for (int j = 0; j < 8; ++j) pp[(long)j * LL] = a[j];
}

// ---------------- K13b: t2 = sum 4 partials + bias ----------------
__global__ void k_conv2sum(const float* __restrict__ part, const float* __restrict__ b2,
                           float* __restrict__ t2) {
    int idx = blockIdx.x * blockDim.x + threadIdx.x;
    if (idx >= 96 * LL) return;
    int l = idx & (LL - 1);
    int oc = idx >> 13;
    float s = b2[oc];
    #pragma unroll
    for (int isp = 0; isp < 4; ++isp)
        s += part[((long)(isp * 96 + oc)) * LL + l];
    t2[oc * LL + l] = s;
}

// ---------------- K14a: per-channel mean ----------------
__global__ void k_mean(const float* __restrict__ t2, float* __restrict__ mbuf) {
    __shared__ float sm[256];
    int c = blockIdx.x;
    float a = 0.f;
    for (int l = threadIdx.x; l < LL; l += 256) a += t2[c * LL + l];
    sm[threadIdx.x] = a;
    __syncthreads();
    for (int o = 128; o > 0; o >>= 1) {
        if (threadIdx.x < o) sm[threadIdx.x] += sm[threadIdx.x + o];
        __syncthreads();
    }
    if (threadIdx.x == 0) mbuf[c] = sm[0] * (1.f / LL);
}

// ---------------- K14b: channel-attention MLP ----------------
__global__ void k_mlp(const float* __restrict__ mbuf, const float* __restrict__ w1,
                      const float* __restrict__ b1, const float* __restrict__ w2,
                      const float* __restrict__ b2, float* __restrict__ v2) {
    __shared__ float v[48];
    int t = threadIdx.x;
    if (t < 48) {
        float s = b1[t];
        for (int c = 0; c < 96; ++c) s += mbuf[c] * w1[t * 96 + c];
        v[t] = fmaxf(s, 0.f);
    }
    __syncthreads();
    if (t < 96) {
        float s = b2[t];
        for (int j = 0; j < 48; ++j) s += v[j] * w2[t * 48 + j];
        v2[t] = 1.f / (1.f + __expf(-s));
    }
}

// ---------------- K15: final residual ----------------
__global__ void k_final(const float* __restrict__ xafter, const float* __restrict__ skip2,
                        const float* __restrict__ t2, const float* __restrict__ v2,
                        float* __restrict__ out) {
    int idx = blockIdx.x * blockDim.x + threadIdx.x;
    if (idx >= LL * CC) return;
    int c = idx % CC;
    int l = idx / CC;
    out[l * CC + c] = xafter[l * CC + c] * skip2[c] + t2[c * LL + l] * v2[c];
}

// ---------------- workspace layout (float offsets) ----------------
static const size_t OFF_XS     = 0;          // 8*96*8192 (xs -> ys; conv partials after combine)
static const size_t OFF_Z      = 6291456;    // 786432 (z channel-major)
static const size_t OFF_XCM    = 7077888;    // 786432 (pre-conv x; reused as acc)
static const size_t OFF_XN     = 7864320;    // 786432 (xn_cm; reused as y)
static const size_t OFF_DTRAW  = 8650752;    // 393216
static const size_t OFF_BB     = 9043968;    // 1048576
static const size_t OFF_CB     = 10092544;   // 1048576
static const size_t OFF_XAFTER = 11141120;   // 786432 (scan: Ap reuses this)
static const size_t OFF_Y2     = 11927552;   // 786432 (scan: Bc reuses this)
static const size_t OFF_T1     = 12713984;   // 262144
static const size_t OFF_T2     = 12976128;   // 786432 (scan: hs reuses this)
static const size_t OFF_MV     = 13762560;   // 256
static const size_t OFF_WT1    = 13762816;   // 82944
static const size_t OFF_WT2    = 13845760;   // 82944
static const size_t OFF_IPT    = 13928704;   // 18432
static const size_t OFF_XPT    = 13947136;   // 29184  (end ~13976320 fl = 55.9 MB)

extern "C" void kernel_launch(void* const* d_in, const int* in_sizes, int n_in,
                              void* d_out, int out_size, void* d_ws, size_t ws_size,
                              hipStream_t stream) {
    const float* inp    = (const float*)d_in[0];
    const float* ln1_w  = (const float*)d_in[2];
    const float* ln1_b  = (const float*)d_in[3];
    const float* skip1  = (const float*)d_in[4];
    const float* skip2  = (const float*)d_in[5];
    const float* ln2_w  = (const float*)d_in[6];
    const float* ln2_b  = (const float*)d_in[7];
    const float* inpj   = (const float*)d_in[8];
    const float* conv_w = (const float*)d_in[9];
    const float* conv_b = (const float*)d_in[10];
    const float* xpw    = (const float*)d_in[11];
    const float* dt_w   = (const float*)d_in[12];
    const float* dt_b   = (const float*)d_in[13];
    const float* A_logs = (const float*)d_in[14];
    const float* Ds     = (const float*)d_in[15];
    const float* onw    = (const float*)d_in[16];
    const float* onb    = (const float*)d_in[17];
    const float* opw    = (const float*)d_in[18];
    const float* cab_w1 = (const float*)d_in[19];
    const float* cab_b1 = (const float*)d_in[20];
    const float* cab_w2 = (const float*)d_in[21];
    const float* cab_b2 = (const float*)d_in[22];
    const float* ca_w1  = (const float*)d_in[23];
    const float* ca_b1  = (const float*)d_in[24];
    const float* ca_w2  = (const float*)d_in[25];
    const float* ca_b2  = (const float*)d_in[26];

    float* ws = (float*)d_ws;
    float* xs     = ws + OFF_XS;
    float* zbuf   = ws + OFF_Z;
    float* xcm    = ws + OFF_XCM;
    float* xn     = ws + OFF_XN;
    float* dtraw  = ws + OFF_DTRAW;
    float* Bb     = ws + OFF_BB;
    float* Cb     = ws + OFF_CB;
    float* xafter = ws + OFF_XAFTER;
    float* y2     = ws + OFF_Y2;
    float* t1     = ws + OFF_T1;
    float* t2     = ws + OFF_T2;
    float* mv     = ws + OFF_MV;
    float* wT1    = ws + OFF_WT1;
    float* wT2    = ws + OFF_WT2;
    float* ipT    = ws + OFF_IPT;
    float* xpT    = ws + OFF_XPT;
    float* acc    = xcm;                 // reuse (xcm dead after dwconv)
    float* ybuf   = xn;                  // reuse (xn dead after inproj)
    float* Ap     = xafter;              // reuse (xafter written at k_outproj)
    float* Bc     = y2;                  // reuse (y2 written at k_ln2)
    float* hst    = t2;                  // reuse (t2 written at k_conv2sum)
    float* part1  = xs;                  // 8*32*8192 (xs dead after combine)
    float* part2  = xs + 2097152;        // 4*96*8192

    float* out = (float*)d_out;
    #define GRID(n) dim3((unsigned)(((n) + 255) / 256)), dim3(256)

    hipLaunchKernelGGL(k_ln1,     GRID(LL),                   0, stream, inp, ln1_w, ln1_b, xn);
    hipLaunchKernelGGL(k_wtrans,  GRID(82944),                0, stream, inpj, xpw, cab_w1, cab_w2, ipT, xpT, wT1, wT2);
    hipLaunchKernelGGL(k_inproj,  dim3(768), dim3(256),       0, stream, xn, ipT, xcm, zbuf);
    hipLaunchKernelGGL(k_dwconv,  GRID(DINc * LL),            0, stream, xcm, conv_w, conv_b, xs);
    hipLaunchKernelGGL(k_perm,    GRID(7 * DINc * LL),        0, stream, xs);
    hipLaunchKernelGGL(k_xdbl,    dim3(256), dim3(256),       0, stream, xs, xpT, dtraw, Bb, Cb);
    hipLaunchKernelGGL(k_scan1,   GRID(KK * DINc * NCH * NN), 0, stream, xs, dtraw, Bb, A_logs, dt_w, dt_b, Ap, Bc);
    hipLaunchKernelGGL(k_scan2,   GRID(KK * DINc * NN),       0, stream, Ap, Bc, hst);
    hipLaunchKernelGGL(k_scan3,   GRID(KK * DINc * NCH * NN), 0, stream, xs, dtraw, Bb, Cb, A_logs, dt_w, dt_b, Ds, hst);
    hipLaunchKernelGGL(k_combine, GRID(LL * DINc),            0, stream, xs, acc);
    hipLaunchKernelGGL(k_outnorm, GRID(LL),                   0, stream, acc, zbuf, onw, onb, ybuf);
    hipLaunchKernelGGL(k_outproj, GRID(LL * CC),              0, stream, ybuf, opw, inp, skip1, xafter);
    hipLaunchKernelGGL(k_ln2,     GRID(LL),                   0, stream, xafter, ln2_w, ln2_b, y2);
    hipLaunchKernelGGL(k_conv1,   dim3(1024), dim3(256),      0, stream, y2, wT1, part1);
    hipLaunchKernelGGL(k_gelusum, GRID(32 * LL),              0, stream, part1, cab_b1, t1);
    hipLaunchKernelGGL(k_conv2,   dim3(1536), dim3(256),      0, stream, t1, wT2, part2);
    hipLaunchKernelGGL(k_conv2sum,GRID(96 * LL),              0, stream, part2, cab_b2, t2);
    hipLaunchKernelGGL(k_mean,    dim3(96), dim3(256),        0, stream, t2, mv);
    hipLaunchKernelGGL(k_mlp,     dim3(1), dim3(128),         0, stream, mv, ca_w1, ca_b1, ca_w2, ca_b2, mv + 96);
    hipLaunchKernelGGL(k_final,   GRID(LL * CC),              0, stream, xafter, skip2, t2, mv + 96, out);
    #undef GRID
}